// Round 4
// baseline (1152.455 us; speedup 1.0000x reference)
//
#include <hip/hip_runtime.h>
#include <hip/hip_bf16.h>
#include <hip/hip_cooperative_groups.h>
#include <math.h>

namespace cg = cooperative_groups;

#define NTOK   288      // B*L
#define NV     3
#define NTV    864      // NV*NTOK
#define NSEL   3456     // NTV*4
#define DMODEL 512
#define NEXP   16
#define TOPK   4
#define HFF    2048
#define RESN   5000
#define MAXSEG 70

typedef short v8s __attribute__((ext_vector_type(8)));
typedef float v4f __attribute__((ext_vector_type(4)));
typedef unsigned short ushort_t;

__device__ __forceinline__ float gelu_exact(float x) {
    return 0.5f * x * (1.0f + erff(x * 0.70710678118654752f));
}
__device__ __forceinline__ unsigned f2bf1(float f) {
    unsigned u = __builtin_bit_cast(unsigned, f);
    return (u + 0x7fffu + ((u >> 16) & 1u)) >> 16;
}
__device__ __forceinline__ unsigned pack2(float a, float b) {
    return f2bf1(a) | (f2bf1(b) << 16);
}
__device__ __forceinline__ float bf2f(ushort_t u) {
    return __builtin_bit_cast(float, (unsigned)u << 16);
}

// ---------------- K0: views + router + top-k (writes v in bf16) ----------------
__global__ __launch_bounds__(256) void build_tokens(
    const int* __restrict__ Z,
    const float* __restrict__ emb0, const float* __restrict__ p0w, const float* __restrict__ p0b,
    const float* __restrict__ emb1, const float* __restrict__ p1w, const float* __restrict__ p1b,
    const float* __restrict__ emb2, const float* __restrict__ p2w, const float* __restrict__ p2b,
    const float* __restrict__ keys, const float* __restrict__ router_w, const float* __restrict__ router_b,
    ushort_t* __restrict__ vbf, float* __restrict__ w4, int* __restrict__ idx4)
{
    int tv = blockIdx.x;
    int vi = tv / NTOK, t = tv % NTOK;
    int tid = threadIdx.x;

    const float* emb; const float* pw; const float* pb; int F;
    if (vi == 0)      { emb = emb0; pw = p0w; pb = p0b; F = 200; }
    else if (vi == 1) { emb = emb1; pw = p1w; pb = p1b; F = 132; }
    else              { emb = emb2; pw = p2w; pb = p2b; F = 112; }
    const float* rw = router_w + (size_t)vi * DMODEL * NEXP;
    const float* rb = router_b + vi * NEXP;

    __shared__ float er[200];
    __shared__ float vs[DMODEL];
    __shared__ float red[256];
    __shared__ float logits[NEXP];
    __shared__ float vsq_s;

    int z = Z[t];
    for (int f = tid; f < F; f += 256) er[f] = emb[(size_t)z * F + f];
    __syncthreads();

    float a0 = pb[tid], a1 = pb[tid + 256];
    for (int f = 0; f < F; ++f) {
        float e = er[f];
        a0 += e * pw[f * DMODEL + tid];
        a1 += e * pw[f * DMODEL + tid + 256];
    }
    vs[tid] = a0; vs[tid + 256] = a1;
    vbf[(size_t)tv * DMODEL + tid]       = (ushort_t)f2bf1(a0);
    vbf[(size_t)tv * DMODEL + tid + 256] = (ushort_t)f2bf1(a1);

    red[tid] = a0 * a0 + a1 * a1;
    __syncthreads();
    for (int s = 128; s > 0; s >>= 1) { if (tid < s) red[tid] += red[tid + s]; __syncthreads(); }
    if (tid == 0) vsq_s = red[0];
    __syncthreads();
    float vsq = vsq_s;

    int lane = tid & 63, wv = tid >> 6;
    for (int ei = 0; ei < 4; ++ei) {
        int e = wv * 4 + ei;
        float p = 0.0f;
        for (int d = lane; d < DMODEL; d += 64) {
            float vvv = vs[d];
            float kk = keys[e * DMODEL + d];
            p += vvv * rw[d * NEXP + e] - kk * (kk - 2.0f * vvv);
        }
        for (int off = 32; off > 0; off >>= 1) p += __shfl_down(p, off, 64);
        if (lane == 0) logits[e] = -vsq + p + rb[e];
    }
    __syncthreads();

    if (tid == 0) {
        float lv[NEXP];
        for (int e = 0; e < NEXP; ++e) lv[e] = logits[e];
        bool used[NEXP] = {false};
        int   tk[TOPK]; float tval[TOPK];
        for (int k = 0; k < TOPK; ++k) {
            int best = -1; float bv = -1e30f;
            for (int e = 0; e < NEXP; ++e)
                if (!used[e] && lv[e] > bv) { bv = lv[e]; best = e; }
            used[best] = true; tk[k] = best; tval[k] = bv;
        }
        float m = tval[0], sum = 0.0f, ww[TOPK];
        for (int k = 0; k < TOPK; ++k) { ww[k] = expf(tval[k] - m); sum += ww[k]; }
        for (int k = 0; k < TOPK; ++k) {
            w4[tv * TOPK + k] = ww[k] / sum;
            idx4[tv * TOPK + k] = tk[k];
        }
    }
}

// ---------------- K1: compact rows per expert + 64-row segment list ----------------
__global__ __launch_bounds__(256) void route_kernel(
    const int* __restrict__ idx4, int* __restrict__ offs,
    int* __restrict__ rows_tv, int* __restrict__ rows_s,
    int* __restrict__ seg_e, int* __restrict__ seg_r0, int* __restrict__ nseg)
{
    __shared__ int cnt[NEXP], cur[NEXP], offsh[NEXP + 1];
    int tid = threadIdx.x;
    if (tid < NEXP) cnt[tid] = 0;
    __syncthreads();
    for (int s = tid; s < NSEL; s += 256) atomicAdd(&cnt[idx4[s]], 1);
    __syncthreads();
    if (tid == 0) {
        int o = 0;
        for (int e = 0; e < NEXP; ++e) { offsh[e] = o; o += cnt[e]; }
        offsh[NEXP] = o;
        int ns = 0;
        for (int e = 0; e < NEXP; ++e)
            for (int s = offsh[e]; s < offsh[e + 1]; s += 64) {
                seg_e[ns] = e; seg_r0[ns] = s; ++ns;
            }
        nseg[0] = ns;
    }
    __syncthreads();
    if (tid < NEXP) cur[tid] = offsh[tid];
    if (tid <= NEXP) offs[tid] = offsh[tid];
    __syncthreads();
    for (int s = tid; s < NSEL; s += 256) {
        int e = idx4[s];
        int pos = atomicAdd(&cur[e], 1);
        rows_tv[pos] = s >> 2;
        rows_s[pos]  = s;
    }
}

// ---------------- transpose tile helper: [K][N] -> [N][K] bf16 ----------------
__device__ __forceinline__ void tile_transpose(
    const float* __restrict__ src_b, ushort_t* __restrict__ out_b,
    int K, int N, int k0, int n0, int tid)
{
    __shared__ ushort_t T[64 * 72];
    int r = tid >> 2, c = tid & 3;
    const float* src = src_b + (size_t)(k0 + r) * N + n0 + c * 16;
    float4 f0 = *(const float4*)(src + 0);
    float4 f1 = *(const float4*)(src + 4);
    float4 f2 = *(const float4*)(src + 8);
    float4 f3 = *(const float4*)(src + 12);
    uint4 u0, u1;
    u0.x = pack2(f0.x, f0.y); u0.y = pack2(f0.z, f0.w);
    u0.z = pack2(f1.x, f1.y); u0.w = pack2(f1.z, f1.w);
    u1.x = pack2(f2.x, f2.y); u1.y = pack2(f2.z, f2.w);
    u1.z = pack2(f3.x, f3.y); u1.w = pack2(f3.z, f3.w);
    *(uint4*)&T[r * 72 + c * 16]     = u0;
    *(uint4*)&T[r * 72 + c * 16 + 8] = u1;
    __syncthreads();
    uint4 o0, o1;
#pragma unroll
    for (int j = 0; j < 16; j += 2) {
        unsigned lo = T[(c * 16 + j)     * 72 + r];
        unsigned hi = T[(c * 16 + j + 1) * 72 + r];
        if (j < 8) ((unsigned*)&o0)[j >> 1] = lo | (hi << 16);
        else       ((unsigned*)&o1)[(j - 8) >> 1] = lo | (hi << 16);
    }
    ushort_t* dst = out_b + (size_t)(n0 + r) * K + k0 + c * 16;
    *(uint4*)(dst)     = o0;
    *(uint4*)(dst + 8) = o1;
}

__global__ __launch_bounds__(256) void transpose_to_bf16(
    const float* __restrict__ in, ushort_t* __restrict__ out, int K, int N)
{
    size_t boff = (size_t)blockIdx.z * (size_t)K * N;
    tile_transpose(in + boff, out + boff, K, N, blockIdx.y * 64, blockIdx.x * 64, threadIdx.x);
}

__global__ __launch_bounds__(256) void transpose_jobs(
    const float* __restrict__ qkvw, const float* __restrict__ aow,
    const float* __restrict__ fw1,  const float* __restrict__ fw2,
    ushort_t* __restrict__ qkvwt, ushort_t* __restrict__ aowt,
    ushort_t* __restrict__ fw1t,  ushort_t* __restrict__ fw2t)
{
    int b = blockIdx.x;
    const float* src; ushort_t* dst; int K, N, nt;
    if (b < 576)       { b -= 0;    src = qkvw; dst = qkvwt; K = 512;  N = 1536; nt = 24; }
    else if (b < 768)  { b -= 576;  src = aow;  dst = aowt;  K = 512;  N = 512;  nt = 8;  }
    else if (b < 1536) { b -= 768;  src = fw1;  dst = fw1t;  K = 512;  N = 2048; nt = 32; }
    else               { b -= 1536; src = fw2;  dst = fw2t;  K = 2048; N = 512;  nt = 8;  }
    int per = nt * (K / 64);
    int z = b / per, r = b % per;
    int n0 = (r % nt) * 64, k0 = (r / nt) * 64;
    size_t boff = (size_t)z * (size_t)K * N;
    tile_transpose(src + boff, dst + boff, K, N, k0, n0, threadIdx.x);
}

// ---------------- MoE phase 1: segment-parallel, one 64x64 tile per block ----------------
__global__ __launch_bounds__(256) void moe_gemm1(
    const ushort_t* __restrict__ vbf, const int* __restrict__ rows_tv,
    const int* __restrict__ offs,
    const int* __restrict__ seg_e, const int* __restrict__ seg_r0, const int* __restrict__ nseg,
    const ushort_t* __restrict__ wt, const float* __restrict__ eb1, ushort_t* __restrict__ h)
{
    if ((int)blockIdx.y >= nseg[0]) return;
    int e = seg_e[blockIdx.y], r0 = seg_r0[blockIdx.y];
    int rend = offs[e + 1];
    int n0 = blockIdx.x * 64;
    const ushort_t* wte = wt + (size_t)e * HFF * DMODEL;
    const float* bias = eb1 + (size_t)e * HFF;
    __shared__ ushort_t Bs[64 * 64];
    int tid = threadIdx.x, wv = tid >> 6, lane = tid & 63, lm = lane & 15, lq = lane >> 4;
    int srow = tid >> 2, sk = (tid & 3) * 16;
    const ushort_t* wrow = wte + (size_t)(n0 + srow) * DMODEL + sk;

    int rA = min(r0 + wv * 16 + lm, rend - 1);
    const ushort_t* arow = vbf + (size_t)rows_tv[rA] * DMODEL;

    v4f acc[4];
#pragma unroll
    for (int nt = 0; nt < 4; ++nt) acc[nt] = (v4f){0.f, 0.f, 0.f, 0.f};

    for (int kp = 0; kp < DMODEL; kp += 64) {
        *(uint4*)&Bs[srow * 64 + sk]     = *(const uint4*)(wrow + kp);
        *(uint4*)&Bs[srow * 64 + sk + 8] = *(const uint4*)(wrow + kp + 8);
        __syncthreads();
#pragma unroll
        for (int s = 0; s < 64; s += 32) {
            v8s a = *(const v8s*)(arow + kp + s + lq * 8);
#pragma unroll
            for (int nt = 0; nt < 4; ++nt) {
                v8s b = *(const v8s*)&Bs[(nt * 16 + lm) * 64 + s + lq * 8];
                acc[nt] = __builtin_amdgcn_mfma_f32_16x16x32_bf16(a, b, acc[nt], 0, 0, 0);
            }
        }
        __syncthreads();
    }
#pragma unroll
    for (int nt = 0; nt < 4; ++nt) {
        int col = n0 + nt * 16 + lm;
        float bv = bias[col];
#pragma unroll
        for (int i = 0; i < 4; ++i) {
            int row = r0 + wv * 16 + lq * 4 + i;
            if (row < rend) {
                float val = gelu_exact(acc[nt][i] + bv);
                h[(size_t)row * HFF + col] = (ushort_t)f2bf1(val);
            }
        }
    }
}

// ---------------- MoE phase 2: segment-parallel, K-split z=2 ----------------
__global__ __launch_bounds__(256) void moe_gemm2(
    const ushort_t* __restrict__ h, const int* __restrict__ rows_s,
    const int* __restrict__ offs,
    const int* __restrict__ seg_e, const int* __restrict__ seg_r0, const int* __restrict__ nseg,
    const ushort_t* __restrict__ wt, const float* __restrict__ eb2, float* __restrict__ yall)
{
    if ((int)blockIdx.y >= nseg[0]) return;
    int e = seg_e[blockIdx.y], r0 = seg_r0[blockIdx.y];
    int rend = offs[e + 1];
    int n0 = blockIdx.x * 64;
    int z = blockIdx.z;
    int kp0 = z * (HFF / 2);
    const ushort_t* wte = wt + (size_t)e * DMODEL * HFF;
    const float* bias = eb2 + (size_t)e * DMODEL;
    float* yz = yall + (size_t)z * NSEL * DMODEL;
    __shared__ ushort_t Bs[64 * 64];
    int tid = threadIdx.x, wv = tid >> 6, lane = tid & 63, lm = lane & 15, lq = lane >> 4;
    int srow = tid >> 2, sk = (tid & 3) * 16;
    const ushort_t* wrow = wte + (size_t)(n0 + srow) * HFF + kp0 + sk;

    int rA = min(r0 + wv * 16 + lm, rend - 1);
    const ushort_t* arow = h + (size_t)rA * HFF + kp0;

    v4f acc[4];
#pragma unroll
    for (int nt = 0; nt < 4; ++nt) acc[nt] = (v4f){0.f, 0.f, 0.f, 0.f};

    for (int kp = 0; kp < HFF / 2; kp += 64) {
        *(uint4*)&Bs[srow * 64 + sk]     = *(const uint4*)(wrow + kp);
        *(uint4*)&Bs[srow * 64 + sk + 8] = *(const uint4*)(wrow + kp + 8);
        __syncthreads();
#pragma unroll
        for (int s = 0; s < 64; s += 32) {
            v8s a = *(const v8s*)(arow + kp + s + lq * 8);
#pragma unroll
            for (int nt = 0; nt < 4; ++nt) {
                v8s b = *(const v8s*)&Bs[(nt * 16 + lm) * 64 + s + lq * 8];
                acc[nt] = __builtin_amdgcn_mfma_f32_16x16x32_bf16(a, b, acc[nt], 0, 0, 0);
            }
        }
        __syncthreads();
    }
#pragma unroll
    for (int nt = 0; nt < 4; ++nt) {
        int col = n0 + nt * 16 + lm;
        float bv = (z == 0) ? bias[col] : 0.0f;
#pragma unroll
        for (int i = 0; i < 4; ++i) {
            int row = r0 + wv * 16 + lq * 4 + i;
            if (row < rend) {
                yz[(size_t)rows_s[row] * DMODEL + col] = acc[nt][i] + bv;
            }
        }
    }
}

// ---------------- fuse: weighted MoE gather (2 K-split partials) + PE ----------------
__global__ __launch_bounds__(256) void fuse_kernel(
    const float* __restrict__ y_all, const float* __restrict__ w4,
    const float* __restrict__ frac, float* __restrict__ x, ushort_t* __restrict__ xbf)
{
    int t = blockIdx.x;
    int tid = threadIdx.x;
    __shared__ float wsh[12];
    __shared__ int idxsh[2];
    if (tid < 12) {
        int vi = tid >> 2, kk = tid & 3;
        wsh[tid] = w4[((size_t)vi * NTOK + t) * TOPK + kk];
    }
    if (tid == 0) {
        double r = (double)frac[t];
        double rl = fmax(r, 1.0 / RESN);
        int il = (int)rint(rl * RESN) - 1;
        idxsh[0] = min(max(il, 0), RESN - 1);
        double lg = log2(r);
        double rg = 0.0025 * lg * lg;
        rg = fmin(rg, 1.0);
        rg = fmax(rg, 1.0 / RESN);
        int ig = (int)rint(rg * RESN) - 1;
        idxsh[1] = min(max(ig, 0), RESN - 1);
    }
    __syncthreads();
    for (int d = tid; d < DMODEL; d += 256) {
        float acc = 0.0f;
        for (int c = 0; c < 12; ++c) {
            int vi = c >> 2, kk = c & 3;
            size_t s = ((size_t)vi * NTOK + t) * TOPK + kk;
            float y = y_all[s * DMODEL + d] + y_all[(size_t)NSEL * DMODEL + s * DMODEL + d];
            acc += wsh[c] * y;
        }
        int cc  = (d < 256) ? d : d - 256;
        int idx = (d < 256) ? idxsh[0] : idxsh[1];
        double arg = (double)idx / pow(50.0, 2.0 * (double)cc / 256.0);
        double pe = (cc & 1) ? cos(arg) : sin(arg);
        float val = acc + (float)pe;
        x[(size_t)t * DMODEL + d] = val;
        xbf[(size_t)t * DMODEL + d] = (ushort_t)f2bf1(val);
    }
}

// ---------------- per-wave 16x64 GEMM unit (bf16 A [*][K], Wt [N][K]) ----------------
__device__ __forceinline__ void gemm_wave_unit(
    const ushort_t* __restrict__ A, int K, const ushort_t* __restrict__ Wt,
    int m0, int n0, int kp0, int Klen, int lm, int lq, v4f acc[4])
{
    const ushort_t* arow  = A  + (size_t)(m0 + lm) * K + kp0;
    const ushort_t* wrow0 = Wt + (size_t)(n0 + lm) * K + kp0;
    for (int ks = 0; ks < Klen; ks += 32) {
        v8s a = *(const v8s*)(arow + ks + lq * 8);
#pragma unroll
        for (int nt = 0; nt < 4; ++nt) {
            v8s b = *(const v8s*)(wrow0 + (size_t)nt * 16 * K + ks + lq * 8);
            acc[nt] = __builtin_amdgcn_mfma_f32_16x16x32_bf16(a, b, acc[nt], 0, 0, 0);
        }
    }
}

// ---------------- cooperative transformer: whole 3-layer stack, one launch ----------------
__global__ __launch_bounds__(256) void transformer_coop(
    float* __restrict__ xbuf, ushort_t* __restrict__ xbf,
    ushort_t* __restrict__ qkvb, ushort_t* __restrict__ obf,
    float* __restrict__ tmp, ushort_t* __restrict__ f1b,
    const ushort_t* __restrict__ qkvwt, const ushort_t* __restrict__ aowt,
    const ushort_t* __restrict__ fw1t,  const ushort_t* __restrict__ fw2t,
    const float* __restrict__ qkv_b, const float* __restrict__ aob,
    const float* __restrict__ ln1g, const float* __restrict__ ln1b,
    const float* __restrict__ ln2g, const float* __restrict__ ln2b,
    const float* __restrict__ fb1, const float* __restrict__ fb2,
    const float* __restrict__ frac, float* __restrict__ out)
{
    cg::grid_group grid = cg::this_grid();
    int tid = threadIdx.x, lane = tid & 63, wv = tid >> 6;
    int gw = blockIdx.x * 4 + wv;            // 0..1023
    int lm = lane & 15, lq = lane >> 4;

    __shared__ float q[9][64], k[9][64], v[9][64], sc[81], pmat[9][9];

    for (int layer = 0; layer < 3; ++layer) {
        const ushort_t* Wq = qkvwt + (size_t)layer * 1536 * 512;
        const ushort_t* Wo = aowt  + (size_t)layer * 512 * 512;
        const ushort_t* W1 = fw1t  + (size_t)layer * 2048 * 512;
        const ushort_t* W2 = fw2t  + (size_t)layer * 512 * 2048;
        const float* bq = qkv_b + layer * 1536;
        const float* bo = aob + layer * 512;
        const float* b1 = fb1 + layer * 2048;
        const float* b2 = fb2 + layer * 512;

        // --- A: qkv = xbf @ Wq^T + bq  (18 m x 24 n = 432 wave units) ---
        if (gw < 432) {
            int m0 = (gw / 24) * 16, n0 = (gw % 24) * 64;
            v4f acc[4];
#pragma unroll
            for (int nt = 0; nt < 4; ++nt) acc[nt] = (v4f){0.f, 0.f, 0.f, 0.f};
            gemm_wave_unit(xbf, 512, Wq, m0, n0, 0, 512, lm, lq, acc);
#pragma unroll
            for (int nt = 0; nt < 4; ++nt) {
                int col = n0 + nt * 16 + lm;
                float bv = bq[col];
#pragma unroll
                for (int i = 0; i < 4; ++i) {
                    int row = m0 + lq * 4 + i;
                    qkvb[(size_t)row * 1536 + col] = (ushort_t)f2bf1(acc[nt][i] + bv);
                }
            }
        }
        grid.sync();

        // --- B: attention, one (b,h) per block (256 blocks) ---
        {
            int bh = blockIdx.x;
            int b = bh >> 3, hh = bh & 7, t0 = b * 9;
            for (int idx = tid; idx < 9 * 64; idx += 256) {
                int i = idx >> 6, d = idx & 63;
                const ushort_t* row = qkvb + (size_t)(t0 + i) * 1536 + hh * 64 + d;
                q[i][d] = bf2f(row[0]); k[i][d] = bf2f(row[512]); v[i][d] = bf2f(row[1024]);
            }
            __syncthreads();
            for (int ij = tid; ij < 81; ij += 256) {
                int i = ij / 9, j = ij % 9;
                float s = 0.0f;
                for (int d = 0; d < 64; ++d) s += q[i][d] * k[j][d];
                sc[ij] = s * 0.125f;
            }
            __syncthreads();
            if (tid < 9) {
                float m = -1e30f;
                for (int j = 0; j < 9; ++j) m = fmaxf(m, sc[tid * 9 + j]);
                float sum = 0.0f, e[9];
                for (int j = 0; j < 9; ++j) { e[j] = expf(sc[tid * 9 + j] - m); sum += e[j]; }
                for (int j = 0; j < 9; ++j) pmat[tid][j] = e[j] / sum;
            }
            __syncthreads();
            for (int idx = tid; idx < 576; idx += 256) {
                int i = idx >> 6, d = idx & 63;
                float acc = 0.0f;
                for (int j = 0; j < 9; ++j) acc += pmat[i][j] * v[j][d];
                obf[(size_t)(t0 + i) * 512 + hh * 64 + d] = (ushort_t)f2bf1(acc);
            }
        }
        grid.sync();

        // --- C: oproj partials (18 m x 8 n x 2 kz = 288 units) ---
        if (gw < 288) {
            int z = gw / 144, rest = gw % 144;
            int m0 = (rest / 8) * 16, n0 = (rest % 8) * 64;
            v4f acc[4];
#pragma unroll
            for (int nt = 0; nt < 4; ++nt) acc[nt] = (v4f){0.f, 0.f, 0.f, 0.f};
            gemm_wave_unit(obf, 512, Wo, m0, n0, z * 256, 256, lm, lq, acc);
            float* tz = tmp + (size_t)z * NTOK * DMODEL;
#pragma unroll
            for (int nt = 0; nt < 4; ++nt) {
                int col = n0 + nt * 16 + lm;
                float bv = (z == 0) ? bo[col] : 0.0f;
#pragma unroll
                for (int i = 0; i < 4; ++i) {
                    int row = m0 + lq * 4 + i;
                    tz[(size_t)row * 512 + col] = acc[nt][i] + bv;
                }
            }
        }
        grid.sync();

        // --- D: residual + ln1 (288 token wave units) ---
        if (gw < NTOK) {
            int t = gw;
            size_t base = (size_t)t * DMODEL;
            int c0 = lane * 8;
            float vals[8];
            *(float4*)(vals)     = *(const float4*)(xbuf + base + c0);
            *(float4*)(vals + 4) = *(const float4*)(xbuf + base + c0 + 4);
            for (int z = 0; z < 2; ++z) {
                const float* tz = tmp + (size_t)z * NTOK * DMODEL + base + c0;
                float4 a4 = *(const float4*)tz, b4 = *(const float4*)(tz + 4);
                vals[0] += a4.x; vals[1] += a4.y; vals[2] += a4.z; vals[3] += a4.w;
                vals[4] += b4.x; vals[5] += b4.y; vals[6] += b4.z; vals[7] += b4.w;
            }
            float s = 0.f;
#pragma unroll
            for (int i = 0; i < 8; ++i) s += vals[i];
            for (int off = 1; off < 64; off <<= 1) s += __shfl_xor(s, off, 64);
            float mean = s * (1.0f / DMODEL);
            float vvv = 0.f;
#pragma unroll
            for (int i = 0; i < 8; ++i) { vals[i] -= mean; vvv += vals[i] * vals[i]; }
            for (int off = 1; off < 64; off <<= 1) vvv += __shfl_xor(vvv, off, 64);
            float rstd = rsqrtf(vvv * (1.0f / DMODEL) + 1e-5f);
            const float* g = ln1g + layer * 512 + c0;
            const float* bb = ln1b + layer * 512 + c0;
            float4 g0 = *(const float4*)g, g1 = *(const float4*)(g + 4);
            float4 bb0 = *(const float4*)bb, bb1 = *(const float4*)(bb + 4);
            float gs[8] = {g0.x,g0.y,g0.z,g0.w,g1.x,g1.y,g1.z,g1.w};
            float bs[8] = {bb0.x,bb0.y,bb0.z,bb0.w,bb1.x,bb1.y,bb1.z,bb1.w};
            float o[8]; uint4 pk;
#pragma unroll
            for (int i = 0; i < 8; ++i) o[i] = vals[i] * rstd * gs[i] + bs[i];
            pk.x = pack2(o[0], o[1]); pk.y = pack2(o[2], o[3]);
            pk.z = pack2(o[4], o[5]); pk.w = pack2(o[6], o[7]);
            *(float4*)(xbuf + base + c0)     = make_float4(o[0], o[1], o[2], o[3]);
            *(float4*)(xbuf + base + c0 + 4) = make_float4(o[4], o[5], o[6], o[7]);
            *(uint4*)(xbf + base + c0) = pk;
        }
        grid.sync();

        // --- E: ffn1 relu (18 m x 32 n = 576 units) ---
        if (gw < 576) {
            int m0 = (gw / 32) * 16, n0 = (gw % 32) * 64;
            v4f acc[4];
#pragma unroll
            for (int nt = 0; nt < 4; ++nt) acc[nt] = (v4f){0.f, 0.f, 0.f, 0.f};
            gemm_wave_unit(xbf, 512, W1, m0, n0, 0, 512, lm, lq, acc);
#pragma unroll
            for (int nt = 0; nt < 4; ++nt) {
                int col = n0 + nt * 16 + lm;
                float bv = b1[col];
#pragma unroll
                for (int i = 0; i < 4; ++i) {
                    int row = m0 + lq * 4 + i;
                    float val = fmaxf(acc[nt][i] + bv, 0.f);
                    f1b[(size_t)row * 2048 + col] = (ushort_t)f2bf1(val);
                }
            }
        }
        grid.sync();

        // --- F: ffn2 partials (18 m x 8 n x 4 kz = 576 units) ---
        if (gw < 576) {
            int z = gw / 144, rest = gw % 144;
            int m0 = (rest / 8) * 16, n0 = (rest % 8) * 64;
            v4f acc[4];
#pragma unroll
            for (int nt = 0; nt < 4; ++nt) acc[nt] = (v4f){0.f, 0.f, 0.f, 0.f};
            gemm_wave_unit(f1b, 2048, W2, m0, n0, z * 512, 512, lm, lq, acc);
            float* tz = tmp + (size_t)z * NTOK * DMODEL;
#pragma unroll
            for (int nt = 0; nt < 4; ++nt) {
                int col = n0 + nt * 16 + lm;
                float bv = (z == 0) ? b2[col] : 0.0f;
#pragma unroll
                for (int i = 0; i < 4; ++i) {
                    int row = m0 + lq * 4 + i;
                    tz[(size_t)row * 512 + col] = acc[nt][i] + bv;
                }
            }
        }
        grid.sync();

        // --- G: residual + ln2 (+ final scale on last layer) ---
        if (gw < NTOK) {
            int t = gw;
            size_t base = (size_t)t * DMODEL;
            int c0 = lane * 8;
            float vals[8];
            *(float4*)(vals)     = *(const float4*)(xbuf + base + c0);
            *(float4*)(vals + 4) = *(const float4*)(xbuf + base + c0 + 4);
            for (int z = 0; z < 4; ++z) {
                const float* tz = tmp + (size_t)z * NTOK * DMODEL + base + c0;
                float4 a4 = *(const float4*)tz, b4 = *(const float4*)(tz + 4);
                vals[0] += a4.x; vals[1] += a4.y; vals[2] += a4.z; vals[3] += a4.w;
                vals[4] += b4.x; vals[5] += b4.y; vals[6] += b4.z; vals[7] += b4.w;
            }
            float s = 0.f;
#pragma unroll
            for (int i = 0; i < 8; ++i) s += vals[i];
            for (int off = 1; off < 64; off <<= 1) s += __shfl_xor(s, off, 64);
            float mean = s * (1.0f / DMODEL);
            float vvv = 0.f;
#pragma unroll
            for (int i = 0; i < 8; ++i) { vals[i] -= mean; vvv += vals[i] * vals[i]; }
            for (int off = 1; off < 64; off <<= 1) vvv += __shfl_xor(vvv, off, 64);
            float rstd = rsqrtf(vvv * (1.0f / DMODEL) + 1e-5f);
            const float* g = ln2g + layer * 512 + c0;
            const float* bb = ln2b + layer * 512 + c0;
            float4 g0 = *(const float4*)g, g1 = *(const float4*)(g + 4);
            float4 bb0 = *(const float4*)bb, bb1 = *(const float4*)(bb + 4);
            float gs[8] = {g0.x,g0.y,g0.z,g0.w,g1.x,g1.y,g1.z,g1.w};
            float bs[8] = {bb0.x,bb0.y,bb0.z,bb0.w,bb1.x,bb1.y,bb1.z,bb1.w};
            float o[8]; uint4 pk;
#pragma unroll
            for (int i = 0; i < 8; ++i) o[i] = vals[i] * rstd * gs[i] + bs[i];
            pk.x = pack2(o[0], o[1]); pk.y = pack2(o[2], o[3]);
            pk.z = pack2(o[4], o[5]); pk.w = pack2(o[6], o[7]);
            *(float4*)(xbuf + base + c0)     = make_float4(o[0], o[1], o[2], o[3]);
            *(float4*)(xbuf + base + c0 + 4) = make_float4(o[4], o[5], o[6], o[7]);
            *(uint4*)(xbf + base + c0) = pk;
            if (layer == 2) {
                float fr = frac[t];
                *(float4*)(out + base + c0)     = make_float4(o[0]*fr, o[1]*fr, o[2]*fr, o[3]*fr);
                *(float4*)(out + base + c0 + 4) = make_float4(o[4]*fr, o[5]*fr, o[6]*fr, o[7]*fr);
            }
        }
        if (layer < 2) grid.sync();
    }
}

extern "C" void kernel_launch(void* const* d_in, const int* in_sizes, int n_in,
                              void* d_out, int out_size, void* d_ws, size_t ws_size,
                              hipStream_t stream) {
    const int*   Z      = (const int*)d_in[0];
    const float* frac   = (const float*)d_in[1];
    const float* emb0   = (const float*)d_in[2];
    const float* p0w    = (const float*)d_in[3];
    const float* p0b    = (const float*)d_in[4];
    const float* emb1   = (const float*)d_in[5];
    const float* p1w    = (const float*)d_in[6];
    const float* p1b    = (const float*)d_in[7];
    const float* emb2   = (const float*)d_in[8];
    const float* p2w    = (const float*)d_in[9];
    const float* p2b    = (const float*)d_in[10];
    const float* keys   = (const float*)d_in[11];
    const float* rw     = (const float*)d_in[12];
    const float* rb     = (const float*)d_in[13];
    const float* ew1    = (const float*)d_in[14];
    const float* eb1    = (const float*)d_in[15];
    const float* ew2    = (const float*)d_in[16];
    const float* eb2    = (const float*)d_in[17];
    const float* qkv_w  = (const float*)d_in[18];
    const float* qkv_b  = (const float*)d_in[19];
    const float* aow    = (const float*)d_in[20];
    const float* aob    = (const float*)d_in[21];
    const float* ln1g   = (const float*)d_in[22];
    const float* ln1b   = (const float*)d_in[23];
    const float* ln2g   = (const float*)d_in[24];
    const float* ln2b   = (const float*)d_in[25];
    const float* fw1    = (const float*)d_in[26];
    const float* fb1    = (const float*)d_in[27];
    const float* fw2    = (const float*)d_in[28];
    const float* fb2    = (const float*)d_in[29];
    float* out = (float*)d_out;

    // workspace layout
    char* p = (char*)d_ws;
    char* U = p;
    ushort_t* vbf   = (ushort_t*)U;                               // 864*512*2
    ushort_t* h     = (ushort_t*)(U + 884736);                    // 3456*2048*2
    float*    yall  = (float*)(U + 884736 + 14155776);            // 2*3456*512*4
    ushort_t* qkvwt = (ushort_t*)U;                               // 3*1536*512*2 (after fuse)
    ushort_t* aowt  = qkvwt + 3 * 1536 * 512;
    ushort_t* fw1t  = aowt  + 3 * 512 * 512;
    ushort_t* fw2t  = fw1t  + 3 * 2048 * 512;
    p = U + 884736 + 14155776 + 14155776;
    float* xbuf = (float*)p;            p += 288 * 512 * 4;
    ushort_t* xbf = (ushort_t*)p;       p += 288 * 512 * 2;
    ushort_t* qkvb = (ushort_t*)p;      p += 288 * 1536 * 2;
    ushort_t* obf = (ushort_t*)p;       p += 288 * 512 * 2;
    float* tmp  = (float*)p;            p += 4 * 288 * 512 * 4;
    ushort_t* f1b = (ushort_t*)p;       p += 288 * 2048 * 2;
    float* w4   = (float*)p;            p += 3456 * 4;
    int* idx4   = (int*)p;              p += 3456 * 4;
    int* offs   = (int*)p;              p += 256;
    int* rows_tv= (int*)p;              p += 3456 * 4;
    int* rows_s = (int*)p;              p += 3456 * 4;
    int* seg_e  = (int*)p;              p += 128 * 4;
    int* seg_r0 = (int*)p;              p += 128 * 4;
    int* nseg   = (int*)p;              p += 256;
    ushort_t* wt = (ushort_t*)p;        // 16*2048*512*2 = 33.6 MB (ew1t then ew2t)

    build_tokens<<<dim3(NTV), dim3(256), 0, stream>>>(
        Z, emb0, p0w, p0b, emb1, p1w, p1b, emb2, p2w, p2b,
        keys, rw, rb, vbf, w4, idx4);
    route_kernel<<<dim3(1), dim3(256), 0, stream>>>(idx4, offs, rows_tv, rows_s,
                                                    seg_e, seg_r0, nseg);

    transpose_to_bf16<<<dim3(2048 / 64, 512 / 64, 16), dim3(256), 0, stream>>>(ew1, wt, 512, 2048);
    moe_gemm1<<<dim3(2048 / 64, MAXSEG), dim3(256), 0, stream>>>(
        vbf, rows_tv, offs, seg_e, seg_r0, nseg, wt, eb1, h);
    transpose_to_bf16<<<dim3(512 / 64, 2048 / 64, 16), dim3(256), 0, stream>>>(ew2, wt, 2048, 512);
    moe_gemm2<<<dim3(512 / 64, MAXSEG, 2), dim3(256), 0, stream>>>(
        h, rows_s, offs, seg_e, seg_r0, nseg, wt, eb2, yall);

    fuse_kernel<<<dim3(NTOK), dim3(256), 0, stream>>>(yall, w4, frac, xbuf, xbf);

    transpose_jobs<<<dim3(2304), dim3(256), 0, stream>>>(
        qkv_w, aow, fw1, fw2, qkvwt, aowt, fw1t, fw2t);

    void* cargs[] = {
        (void*)&xbuf, (void*)&xbf, (void*)&qkvb, (void*)&obf,
        (void*)&tmp, (void*)&f1b,
        (void*)&qkvwt, (void*)&aowt, (void*)&fw1t, (void*)&fw2t,
        (void*)&qkv_b, (void*)&aob,
        (void*)&ln1g, (void*)&ln1b, (void*)&ln2g, (void*)&ln2b,
        (void*)&fb1, (void*)&fb2, (void*)&frac, (void*)&out
    };
    hipLaunchCooperativeKernel((void*)transformer_coop, dim3(256), dim3(256),
                               cargs, 0, stream);
}

// Round 5
// 550.731 us; speedup vs baseline: 2.0926x; 2.0926x over previous
//
#include <hip/hip_runtime.h>
#include <hip/hip_bf16.h>
#include <math.h>

#define NTOK   288      // B*L
#define NV     3
#define NTV    864      // NV*NTOK
#define NSEL   3456     // NTV*4
#define DMODEL 512
#define NEXP   16
#define TOPK   4
#define HFF    2048
#define RESN   5000
#define MAXSEG 70

typedef short v8s __attribute__((ext_vector_type(8)));
typedef float v4f __attribute__((ext_vector_type(4)));
typedef unsigned short ushort_t;

__device__ __forceinline__ float gelu_exact(float x) {
    return 0.5f * x * (1.0f + erff(x * 0.70710678118654752f));
}
__device__ __forceinline__ unsigned f2bf1(float f) {
    unsigned u = __builtin_bit_cast(unsigned, f);
    return (u + 0x7fffu + ((u >> 16) & 1u)) >> 16;
}
__device__ __forceinline__ unsigned pack2(float a, float b) {
    return f2bf1(a) | (f2bf1(b) << 16);
}
__device__ __forceinline__ float bf2f(ushort_t u) {
    return __builtin_bit_cast(float, (unsigned)u << 16);
}

// ---------------- transpose tile helper: [K][N] -> [N][K] bf16 ----------------
__device__ __forceinline__ void tile_transpose(
    const float* __restrict__ src_b, ushort_t* __restrict__ out_b,
    int K, int N, int k0, int n0, int tid)
{
    __shared__ ushort_t T[64 * 72];
    int r = tid >> 2, c = tid & 3;
    const float* src = src_b + (size_t)(k0 + r) * N + n0 + c * 16;
    float4 f0 = *(const float4*)(src + 0);
    float4 f1 = *(const float4*)(src + 4);
    float4 f2 = *(const float4*)(src + 8);
    float4 f3 = *(const float4*)(src + 12);
    uint4 u0, u1;
    u0.x = pack2(f0.x, f0.y); u0.y = pack2(f0.z, f0.w);
    u0.z = pack2(f1.x, f1.y); u0.w = pack2(f1.z, f1.w);
    u1.x = pack2(f2.x, f2.y); u1.y = pack2(f2.z, f2.w);
    u1.z = pack2(f3.x, f3.y); u1.w = pack2(f3.z, f3.w);
    *(uint4*)&T[r * 72 + c * 16]     = u0;
    *(uint4*)&T[r * 72 + c * 16 + 8] = u1;
    __syncthreads();
    uint4 o0, o1;
#pragma unroll
    for (int j = 0; j < 16; j += 2) {
        unsigned lo = T[(c * 16 + j)     * 72 + r];
        unsigned hi = T[(c * 16 + j + 1) * 72 + r];
        if (j < 8) ((unsigned*)&o0)[j >> 1] = lo | (hi << 16);
        else       ((unsigned*)&o1)[(j - 8) >> 1] = lo | (hi << 16);
    }
    ushort_t* dst = out_b + (size_t)(n0 + r) * K + k0 + c * 16;
    *(uint4*)(dst)     = o0;
    *(uint4*)(dst + 8) = o1;
}

// ---------------- build_tokens body (device fn) ----------------
__device__ void build_tokens_body(
    int tv, int tid,
    const int* __restrict__ Z,
    const float* __restrict__ emb0, const float* __restrict__ p0w, const float* __restrict__ p0b,
    const float* __restrict__ emb1, const float* __restrict__ p1w, const float* __restrict__ p1b,
    const float* __restrict__ emb2, const float* __restrict__ p2w, const float* __restrict__ p2b,
    const float* __restrict__ keys, const float* __restrict__ router_w, const float* __restrict__ router_b,
    ushort_t* __restrict__ vbf, float* __restrict__ w4, int* __restrict__ idx4)
{
    int vi = tv / NTOK, t = tv % NTOK;
    const float* emb; const float* pw; const float* pb; int F;
    if (vi == 0)      { emb = emb0; pw = p0w; pb = p0b; F = 200; }
    else if (vi == 1) { emb = emb1; pw = p1w; pb = p1b; F = 132; }
    else              { emb = emb2; pw = p2w; pb = p2b; F = 112; }
    const float* rw = router_w + (size_t)vi * DMODEL * NEXP;
    const float* rb = router_b + vi * NEXP;

    __shared__ float er[200];
    __shared__ float vs[DMODEL];
    __shared__ float red[256];
    __shared__ float logits[NEXP];
    __shared__ float vsq_s;

    int z = Z[t];
    for (int f = tid; f < F; f += 256) er[f] = emb[(size_t)z * F + f];
    __syncthreads();

    float a0 = pb[tid], a1 = pb[tid + 256];
    for (int f = 0; f < F; ++f) {
        float e = er[f];
        a0 += e * pw[f * DMODEL + tid];
        a1 += e * pw[f * DMODEL + tid + 256];
    }
    vs[tid] = a0; vs[tid + 256] = a1;
    vbf[(size_t)tv * DMODEL + tid]       = (ushort_t)f2bf1(a0);
    vbf[(size_t)tv * DMODEL + tid + 256] = (ushort_t)f2bf1(a1);

    red[tid] = a0 * a0 + a1 * a1;
    __syncthreads();
    for (int s = 128; s > 0; s >>= 1) { if (tid < s) red[tid] += red[tid + s]; __syncthreads(); }
    if (tid == 0) vsq_s = red[0];
    __syncthreads();
    float vsq = vsq_s;

    int lane = tid & 63, wv = tid >> 6;
    for (int ei = 0; ei < 4; ++ei) {
        int e = wv * 4 + ei;
        float p = 0.0f;
        for (int d = lane; d < DMODEL; d += 64) {
            float vvv = vs[d];
            float kk = keys[e * DMODEL + d];
            p += vvv * rw[d * NEXP + e] - kk * (kk - 2.0f * vvv);
        }
        for (int off = 32; off > 0; off >>= 1) p += __shfl_down(p, off, 64);
        if (lane == 0) logits[e] = -vsq + p + rb[e];
    }
    __syncthreads();

    if (tid == 0) {
        float lv[NEXP];
        for (int e = 0; e < NEXP; ++e) lv[e] = logits[e];
        bool used[NEXP] = {false};
        int   tk[TOPK]; float tval[TOPK];
        for (int k = 0; k < TOPK; ++k) {
            int best = -1; float bv = -1e30f;
            for (int e = 0; e < NEXP; ++e)
                if (!used[e] && lv[e] > bv) { bv = lv[e]; best = e; }
            used[best] = true; tk[k] = best; tval[k] = bv;
        }
        float m = tval[0], sum = 0.0f, ww[TOPK];
        for (int k = 0; k < TOPK; ++k) { ww[k] = expf(tval[k] - m); sum += ww[k]; }
        for (int k = 0; k < TOPK; ++k) {
            w4[tv * TOPK + k] = ww[k] / sum;
            idx4[tv * TOPK + k] = tk[k];
        }
    }
}

// ---------------- D1: build_tokens (864 blocks) + transpose ew1 (4096 blocks) ----------------
__global__ __launch_bounds__(256) void front_kernel(
    const int* __restrict__ Z,
    const float* __restrict__ emb0, const float* __restrict__ p0w, const float* __restrict__ p0b,
    const float* __restrict__ emb1, const float* __restrict__ p1w, const float* __restrict__ p1b,
    const float* __restrict__ emb2, const float* __restrict__ p2w, const float* __restrict__ p2b,
    const float* __restrict__ keys, const float* __restrict__ router_w, const float* __restrict__ router_b,
    ushort_t* __restrict__ vbf, float* __restrict__ w4, int* __restrict__ idx4,
    const float* __restrict__ ew1, ushort_t* __restrict__ wt)
{
    int tid = threadIdx.x;
    if (blockIdx.x < NTV) {
        build_tokens_body(blockIdx.x, tid, Z, emb0, p0w, p0b, emb1, p1w, p1b,
                          emb2, p2w, p2b, keys, router_w, router_b, vbf, w4, idx4);
    } else {
        int b = blockIdx.x - NTV;           // 0..4095
        int z = b >> 8, r = b & 255;
        int x = r & 31, y = r >> 5;         // 32 n-tiles, 8 k-tiles
        size_t boff = (size_t)z * 512 * 2048;
        tile_transpose(ew1 + boff, wt + boff, 512, 2048, y * 64, x * 64, tid);
    }
}

// ---------------- K1: compact rows per expert + 64-row segment list ----------------
__global__ __launch_bounds__(256) void route_kernel(
    const int* __restrict__ idx4, int* __restrict__ offs,
    int* __restrict__ rows_tv, int* __restrict__ rows_s,
    int* __restrict__ seg_e, int* __restrict__ seg_r0, int* __restrict__ nseg)
{
    __shared__ int cnt[NEXP], cur[NEXP], offsh[NEXP + 1];
    int tid = threadIdx.x;
    if (tid < NEXP) cnt[tid] = 0;
    __syncthreads();
    for (int s = tid; s < NSEL; s += 256) atomicAdd(&cnt[idx4[s]], 1);
    __syncthreads();
    if (tid == 0) {
        int o = 0;
        for (int e = 0; e < NEXP; ++e) { offsh[e] = o; o += cnt[e]; }
        offsh[NEXP] = o;
        int ns = 0;
        for (int e = 0; e < NEXP; ++e)
            for (int s = offsh[e]; s < offsh[e + 1]; s += 64) {
                seg_e[ns] = e; seg_r0[ns] = s; ++ns;
            }
        nseg[0] = ns;
    }
    __syncthreads();
    if (tid < NEXP) cur[tid] = offsh[tid];
    if (tid <= NEXP) offs[tid] = offsh[tid];
    __syncthreads();
    for (int s = tid; s < NSEL; s += 256) {
        int e = idx4[s];
        int pos = atomicAdd(&cur[e], 1);
        rows_tv[pos] = s >> 2;
        rows_s[pos]  = s;
    }
}

__global__ __launch_bounds__(256) void transpose_to_bf16(
    const float* __restrict__ in, ushort_t* __restrict__ out, int K, int N)
{
    size_t boff = (size_t)blockIdx.z * (size_t)K * N;
    tile_transpose(in + boff, out + boff, K, N, blockIdx.y * 64, blockIdx.x * 64, threadIdx.x);
}

__global__ __launch_bounds__(256) void transpose_jobs(
    const float* __restrict__ qkvw, const float* __restrict__ aow,
    const float* __restrict__ fw1,  const float* __restrict__ fw2,
    ushort_t* __restrict__ qkvwt, ushort_t* __restrict__ aowt,
    ushort_t* __restrict__ fw1t,  ushort_t* __restrict__ fw2t)
{
    int b = blockIdx.x;
    const float* src; ushort_t* dst; int K, N, nt;
    if (b < 576)       { b -= 0;    src = qkvw; dst = qkvwt; K = 512;  N = 1536; nt = 24; }
    else if (b < 768)  { b -= 576;  src = aow;  dst = aowt;  K = 512;  N = 512;  nt = 8;  }
    else if (b < 1536) { b -= 768;  src = fw1;  dst = fw1t;  K = 512;  N = 2048; nt = 32; }
    else               { b -= 1536; src = fw2;  dst = fw2t;  K = 2048; N = 512;  nt = 8;  }
    int per = nt * (K / 64);
    int z = b / per, r = b % per;
    int n0 = (r % nt) * 64, k0 = (r / nt) * 64;
    size_t boff = (size_t)z * (size_t)K * N;
    tile_transpose(src + boff, dst + boff, K, N, k0, n0, threadIdx.x);
}

// ---------------- MoE phase 1: segment-parallel, one 64x64 tile per block ----------------
__global__ __launch_bounds__(256) void moe_gemm1(
    const ushort_t* __restrict__ vbf, const int* __restrict__ rows_tv,
    const int* __restrict__ offs,
    const int* __restrict__ seg_e, const int* __restrict__ seg_r0, const int* __restrict__ nseg,
    const ushort_t* __restrict__ wt, const float* __restrict__ eb1, ushort_t* __restrict__ h)
{
    if ((int)blockIdx.y >= nseg[0]) return;
    int e = seg_e[blockIdx.y], r0 = seg_r0[blockIdx.y];
    int rend = offs[e + 1];
    int n0 = blockIdx.x * 64;
    const ushort_t* wte = wt + (size_t)e * HFF * DMODEL;
    const float* bias = eb1 + (size_t)e * HFF;
    __shared__ ushort_t Bs[64 * 64];
    int tid = threadIdx.x, wv = tid >> 6, lane = tid & 63, lm = lane & 15, lq = lane >> 4;
    int srow = tid >> 2, sk = (tid & 3) * 16;
    const ushort_t* wrow = wte + (size_t)(n0 + srow) * DMODEL + sk;

    int rA = min(r0 + wv * 16 + lm, rend - 1);
    const ushort_t* arow = vbf + (size_t)rows_tv[rA] * DMODEL;

    v4f acc[4];
#pragma unroll
    for (int nt = 0; nt < 4; ++nt) acc[nt] = (v4f){0.f, 0.f, 0.f, 0.f};

    for (int kp = 0; kp < DMODEL; kp += 64) {
        *(uint4*)&Bs[srow * 64 + sk]     = *(const uint4*)(wrow + kp);
        *(uint4*)&Bs[srow * 64 + sk + 8] = *(const uint4*)(wrow + kp + 8);
        __syncthreads();
#pragma unroll
        for (int s = 0; s < 64; s += 32) {
            v8s a = *(const v8s*)(arow + kp + s + lq * 8);
#pragma unroll
            for (int nt = 0; nt < 4; ++nt) {
                v8s b = *(const v8s*)&Bs[(nt * 16 + lm) * 64 + s + lq * 8];
                acc[nt] = __builtin_amdgcn_mfma_f32_16x16x32_bf16(a, b, acc[nt], 0, 0, 0);
            }
        }
        __syncthreads();
    }
#pragma unroll
    for (int nt = 0; nt < 4; ++nt) {
        int col = n0 + nt * 16 + lm;
        float bv = bias[col];
#pragma unroll
        for (int i = 0; i < 4; ++i) {
            int row = r0 + wv * 16 + lq * 4 + i;
            if (row < rend) {
                float val = gelu_exact(acc[nt][i] + bv);
                h[(size_t)row * HFF + col] = (ushort_t)f2bf1(val);
            }
        }
    }
}

// ---------------- MoE phase 2: segment-parallel, K-split z=2 ----------------
__global__ __launch_bounds__(256) void moe_gemm2(
    const ushort_t* __restrict__ h, const int* __restrict__ rows_s,
    const int* __restrict__ offs,
    const int* __restrict__ seg_e, const int* __restrict__ seg_r0, const int* __restrict__ nseg,
    const ushort_t* __restrict__ wt, const float* __restrict__ eb2, float* __restrict__ yall)
{
    if ((int)blockIdx.y >= nseg[0]) return;
    int e = seg_e[blockIdx.y], r0 = seg_r0[blockIdx.y];
    int rend = offs[e + 1];
    int n0 = blockIdx.x * 64;
    int z = blockIdx.z;
    int kp0 = z * (HFF / 2);
    const ushort_t* wte = wt + (size_t)e * DMODEL * HFF;
    const float* bias = eb2 + (size_t)e * DMODEL;
    float* yz = yall + (size_t)z * NSEL * DMODEL;
    __shared__ ushort_t Bs[64 * 64];
    int tid = threadIdx.x, wv = tid >> 6, lane = tid & 63, lm = lane & 15, lq = lane >> 4;
    int srow = tid >> 2, sk = (tid & 3) * 16;
    const ushort_t* wrow = wte + (size_t)(n0 + srow) * HFF + kp0 + sk;

    int rA = min(r0 + wv * 16 + lm, rend - 1);
    const ushort_t* arow = h + (size_t)rA * HFF + kp0;

    v4f acc[4];
#pragma unroll
    for (int nt = 0; nt < 4; ++nt) acc[nt] = (v4f){0.f, 0.f, 0.f, 0.f};

    for (int kp = 0; kp < HFF / 2; kp += 64) {
        *(uint4*)&Bs[srow * 64 + sk]     = *(const uint4*)(wrow + kp);
        *(uint4*)&Bs[srow * 64 + sk + 8] = *(const uint4*)(wrow + kp + 8);
        __syncthreads();
#pragma unroll
        for (int s = 0; s < 64; s += 32) {
            v8s a = *(const v8s*)(arow + kp + s + lq * 8);
#pragma unroll
            for (int nt = 0; nt < 4; ++nt) {
                v8s b = *(const v8s*)&Bs[(nt * 16 + lm) * 64 + s + lq * 8];
                acc[nt] = __builtin_amdgcn_mfma_f32_16x16x32_bf16(a, b, acc[nt], 0, 0, 0);
            }
        }
        __syncthreads();
    }
#pragma unroll
    for (int nt = 0; nt < 4; ++nt) {
        int col = n0 + nt * 16 + lm;
        float bv = (z == 0) ? bias[col] : 0.0f;
#pragma unroll
        for (int i = 0; i < 4; ++i) {
            int row = r0 + wv * 16 + lq * 4 + i;
            if (row < rend) {
                yz[(size_t)rows_s[row] * DMODEL + col] = acc[nt][i] + bv;
            }
        }
    }
}

// ---------------- fuse: weighted MoE gather (2 K-split partials) + PE ----------------
__global__ __launch_bounds__(256) void fuse_kernel(
    const float* __restrict__ y_all, const float* __restrict__ w4,
    const float* __restrict__ frac, float* __restrict__ x, ushort_t* __restrict__ xbf)
{
    int t = blockIdx.x;
    int tid = threadIdx.x;
    __shared__ float wsh[12];
    __shared__ int idxsh[2];
    if (tid < 12) {
        int vi = tid >> 2, kk = tid & 3;
        wsh[tid] = w4[((size_t)vi * NTOK + t) * TOPK + kk];
    }
    if (tid == 0) {
        double r = (double)frac[t];
        double rl = fmax(r, 1.0 / RESN);
        int il = (int)rint(rl * RESN) - 1;
        idxsh[0] = min(max(il, 0), RESN - 1);
        double lg = log2(r);
        double rg = 0.0025 * lg * lg;
        rg = fmin(rg, 1.0);
        rg = fmax(rg, 1.0 / RESN);
        int ig = (int)rint(rg * RESN) - 1;
        idxsh[1] = min(max(ig, 0), RESN - 1);
    }
    __syncthreads();
    for (int d = tid; d < DMODEL; d += 256) {
        float acc = 0.0f;
        for (int c = 0; c < 12; ++c) {
            int vi = c >> 2, kk = c & 3;
            size_t s = ((size_t)vi * NTOK + t) * TOPK + kk;
            float y = y_all[s * DMODEL + d] + y_all[(size_t)NSEL * DMODEL + s * DMODEL + d];
            acc += wsh[c] * y;
        }
        int cc  = (d < 256) ? d : d - 256;
        int idx = (d < 256) ? idxsh[0] : idxsh[1];
        double arg = (double)idx / pow(50.0, 2.0 * (double)cc / 256.0);
        double pe = (cc & 1) ? cos(arg) : sin(arg);
        float val = acc + (float)pe;
        x[(size_t)t * DMODEL + d] = val;
        xbf[(size_t)t * DMODEL + d] = (ushort_t)f2bf1(val);
    }
}

// ---------------- per-wave 16x64 GEMM unit (bf16 A [*][K], Wt [N][K]) ----------------
__device__ __forceinline__ void gemm_wave_unit(
    const ushort_t* __restrict__ A, int K, const ushort_t* __restrict__ Wt,
    int m0, int n0, int kp0, int Klen, int lm, int lq, v4f acc[4])
{
    const ushort_t* arow  = A  + (size_t)(m0 + lm) * K + kp0;
    const ushort_t* wrow0 = Wt + (size_t)(n0 + lm) * K + kp0;
    for (int ks = 0; ks < Klen; ks += 32) {
        v8s a = *(const v8s*)(arow + ks + lq * 8);
#pragma unroll
        for (int nt = 0; nt < 4; ++nt) {
            v8s b = *(const v8s*)(wrow0 + (size_t)nt * 16 * K + ks + lq * 8);
            acc[nt] = __builtin_amdgcn_mfma_f32_16x16x32_bf16(a, b, acc[nt], 0, 0, 0);
        }
    }
}

// ---------------- qkv GEMM: 432 wave units (108 blocks) ----------------
__global__ __launch_bounds__(256) void qkv_kernel(
    const ushort_t* __restrict__ xbf, const ushort_t* __restrict__ Wq,
    const float* __restrict__ bq, ushort_t* __restrict__ qkvb)
{
    int tid = threadIdx.x, wv = tid >> 6, lane = tid & 63, lm = lane & 15, lq = lane >> 4;
    int gw = blockIdx.x * 4 + wv;
    int m0 = (gw / 24) * 16, n0 = (gw % 24) * 64;
    v4f acc[4];
#pragma unroll
    for (int nt = 0; nt < 4; ++nt) acc[nt] = (v4f){0.f, 0.f, 0.f, 0.f};
    gemm_wave_unit(xbf, 512, Wq, m0, n0, 0, 512, lm, lq, acc);
#pragma unroll
    for (int nt = 0; nt < 4; ++nt) {
        int col = n0 + nt * 16 + lm;
        float bv = bq[col];
#pragma unroll
        for (int i = 0; i < 4; ++i) {
            int row = m0 + lq * 4 + i;
            qkvb[(size_t)row * 1536 + col] = (ushort_t)f2bf1(acc[nt][i] + bv);
        }
    }
}

// ---------------- attention + oproj + residual + ln1: one block per batch ----------------
__global__ __launch_bounds__(256) void attn_block(
    const ushort_t* __restrict__ qkvb, const ushort_t* __restrict__ Wot,
    const float* __restrict__ bo, float* __restrict__ xbuf, ushort_t* __restrict__ xbf,
    const float* __restrict__ g, const float* __restrict__ bb)
{
    int bbk = blockIdx.x, t0 = bbk * 9;
    int tid = threadIdx.x, wv = tid >> 6, lane = tid & 63, lm = lane & 15, lq = lane >> 4;

    __shared__ ushort_t qkvs[9][1536];
    __shared__ ushort_t osh[16][520];
    __shared__ float sc[8][9][9];
    __shared__ float res[9][512];

    // load qkv tile (9 x 1536)
    for (int idx = tid; idx < 9 * 192; idx += 256) {
        int r = idx / 192, c = (idx % 192) * 8;
        *(uint4*)&qkvs[r][c] = *(const uint4*)(qkvb + (size_t)(t0 + r) * 1536 + c);
    }
    // zero osh (16 x 520)
    for (int idx = tid; idx < 16 * 65; idx += 256) {
        *(uint4*)&osh[idx / 65][(idx % 65) * 8] = (uint4){0, 0, 0, 0};
    }
    __syncthreads();

    // scores: 8 heads x 81 pairs
    for (int idx = tid; idx < 648; idx += 256) {
        int hh = idx / 81, ij = idx % 81, i = ij / 9, j = ij % 9;
        const ushort_t* qr = &qkvs[i][hh * 64];
        const ushort_t* kr = &qkvs[j][512 + hh * 64];
        float s = 0.0f;
        for (int d = 0; d < 64; ++d) s += bf2f(qr[d]) * bf2f(kr[d]);
        sc[hh][i][j] = s * 0.125f;
    }
    __syncthreads();
    // softmax: 72 rows
    if (tid < 72) {
        int hh = tid / 9, i = tid % 9;
        float m = -1e30f;
        for (int j = 0; j < 9; ++j) m = fmaxf(m, sc[hh][i][j]);
        float sum = 0.0f, e[9];
        for (int j = 0; j < 9; ++j) { e[j] = expf(sc[hh][i][j] - m); sum += e[j]; }
        for (int j = 0; j < 9; ++j) sc[hh][i][j] = e[j] / sum;
    }
    __syncthreads();
    // o = p @ v : 8h x 9i x 64d
    for (int idx = tid; idx < 4608; idx += 256) {
        int hh = idx / 576, r = idx % 576, i = r / 64, d = r % 64;
        float acc = 0.0f;
        for (int j = 0; j < 9; ++j) acc += sc[hh][i][j] * bf2f(qkvs[j][1024 + hh * 64 + d]);
        osh[i][hh * 64 + d] = (ushort_t)f2bf1(acc);
    }
    __syncthreads();

    // oproj: wave wv handles n in [wv*128, wv*128+128)
    v4f acc[8];
#pragma unroll
    for (int nt = 0; nt < 8; ++nt) acc[nt] = (v4f){0.f, 0.f, 0.f, 0.f};
    int n0w = wv * 128;
    for (int ks = 0; ks < 512; ks += 32) {
        v8s a = *(const v8s*)&osh[lm][ks + lq * 8];
#pragma unroll
        for (int nt = 0; nt < 8; ++nt) {
            v8s b = *(const v8s*)(Wot + (size_t)(n0w + nt * 16 + lm) * 512 + ks + lq * 8);
            acc[nt] = __builtin_amdgcn_mfma_f32_16x16x32_bf16(a, b, acc[nt], 0, 0, 0);
        }
    }
#pragma unroll
    for (int nt = 0; nt < 8; ++nt) {
        int col = n0w + nt * 16 + lm;
        float bv = bo[col];
#pragma unroll
        for (int i = 0; i < 4; ++i) {
            int row = lq * 4 + i;
            if (row < 9) res[row][col] = acc[nt][i] + bv;
        }
    }
    __syncthreads();

    // residual + ln1: wave wv handles rows wv, wv+4, wv+8
    for (int r = wv; r < 9; r += 4) {
        int t = t0 + r;
        size_t base = (size_t)t * DMODEL;
        int c0 = lane * 8;
        float vals[8];
        float4 x0 = *(const float4*)(xbuf + base + c0);
        float4 x1 = *(const float4*)(xbuf + base + c0 + 4);
        vals[0] = x0.x + res[r][c0 + 0]; vals[1] = x0.y + res[r][c0 + 1];
        vals[2] = x0.z + res[r][c0 + 2]; vals[3] = x0.w + res[r][c0 + 3];
        vals[4] = x1.x + res[r][c0 + 4]; vals[5] = x1.y + res[r][c0 + 5];
        vals[6] = x1.z + res[r][c0 + 6]; vals[7] = x1.w + res[r][c0 + 7];
        float s = 0.f;
#pragma unroll
        for (int i = 0; i < 8; ++i) s += vals[i];
        for (int off = 1; off < 64; off <<= 1) s += __shfl_xor(s, off, 64);
        float mean = s * (1.0f / DMODEL);
        float vvv = 0.f;
#pragma unroll
        for (int i = 0; i < 8; ++i) { vals[i] -= mean; vvv += vals[i] * vals[i]; }
        for (int off = 1; off < 64; off <<= 1) vvv += __shfl_xor(vvv, off, 64);
        float rstd = rsqrtf(vvv * (1.0f / DMODEL) + 1e-5f);
        float4 g0 = *(const float4*)(g + c0), g1 = *(const float4*)(g + c0 + 4);
        float4 b0 = *(const float4*)(bb + c0), b1 = *(const float4*)(bb + c0 + 4);
        float gs[8] = {g0.x,g0.y,g0.z,g0.w,g1.x,g1.y,g1.z,g1.w};
        float bs[8] = {b0.x,b0.y,b0.z,b0.w,b1.x,b1.y,b1.z,b1.w};
        float o[8]; uint4 pk;
#pragma unroll
        for (int i = 0; i < 8; ++i) o[i] = vals[i] * rstd * gs[i] + bs[i];
        pk.x = pack2(o[0], o[1]); pk.y = pack2(o[2], o[3]);
        pk.z = pack2(o[4], o[5]); pk.w = pack2(o[6], o[7]);
        *(float4*)(xbuf + base + c0)     = make_float4(o[0], o[1], o[2], o[3]);
        *(float4*)(xbuf + base + c0 + 4) = make_float4(o[4], o[5], o[6], o[7]);
        *(uint4*)(xbf + base + c0) = pk;
    }
}

// ---------------- ffn1: relu(x @ W1^T + b1), 576 units (144 blocks) ----------------
__global__ __launch_bounds__(256) void ffn1_kernel(
    const ushort_t* __restrict__ xbf, const ushort_t* __restrict__ W1,
    const float* __restrict__ b1, ushort_t* __restrict__ f1b)
{
    int tid = threadIdx.x, wv = tid >> 6, lane = tid & 63, lm = lane & 15, lq = lane >> 4;
    int gw = blockIdx.x * 4 + wv;
    int m0 = (gw / 32) * 16, n0 = (gw % 32) * 64;
    v4f acc[4];
#pragma unroll
    for (int nt = 0; nt < 4; ++nt) acc[nt] = (v4f){0.f, 0.f, 0.f, 0.f};
    gemm_wave_unit(xbf, 512, W1, m0, n0, 0, 512, lm, lq, acc);
#pragma unroll
    for (int nt = 0; nt < 4; ++nt) {
        int col = n0 + nt * 16 + lm;
        float bv = b1[col];
#pragma unroll
        for (int i = 0; i < 4; ++i) {
            int row = m0 + lq * 4 + i;
            f1b[(size_t)row * 2048 + col] = (ushort_t)f2bf1(fmaxf(acc[nt][i] + bv, 0.f));
        }
    }
}

// ---------------- ffn2: K-split z=4 partials, 576 units (144 blocks) ----------------
__global__ __launch_bounds__(256) void ffn2_kernel(
    const ushort_t* __restrict__ f1b, const ushort_t* __restrict__ W2,
    const float* __restrict__ b2, float* __restrict__ tmp)
{
    int tid = threadIdx.x, wv = tid >> 6, lane = tid & 63, lm = lane & 15, lq = lane >> 4;
    int gw = blockIdx.x * 4 + wv;
    int z = gw / 144, rest = gw % 144;
    int m0 = (rest / 8) * 16, n0 = (rest % 8) * 64;
    v4f acc[4];
#pragma unroll
    for (int nt = 0; nt < 4; ++nt) acc[nt] = (v4f){0.f, 0.f, 0.f, 0.f};
    gemm_wave_unit(f1b, 2048, W2, m0, n0, z * 512, 512, lm, lq, acc);
    float* tz = tmp + (size_t)z * NTOK * DMODEL;
#pragma unroll
    for (int nt = 0; nt < 4; ++nt) {
        int col = n0 + nt * 16 + lm;
        float bv = (z == 0) ? b2[col] : 0.0f;
#pragma unroll
        for (int i = 0; i < 4; ++i) {
            int row = m0 + lq * 4 + i;
            tz[(size_t)row * 512 + col] = acc[nt][i] + bv;
        }
    }
}

// ---------------- ln2: residual(4 partials) + LN (+final scale) ----------------
__global__ __launch_bounds__(256) void ln2_kernel(
    float* __restrict__ xbuf, ushort_t* __restrict__ xbf,
    const float* __restrict__ tmp,
    const float* __restrict__ g, const float* __restrict__ bb,
    float* __restrict__ out, const float* __restrict__ frac)
{
    int tid = threadIdx.x, wv = tid >> 6, lane = tid & 63;
    int t = blockIdx.x * 4 + wv;
    size_t base = (size_t)t * DMODEL;
    int c0 = lane * 8;
    float vals[8];
    *(float4*)(vals)     = *(const float4*)(xbuf + base + c0);
    *(float4*)(vals + 4) = *(const float4*)(xbuf + base + c0 + 4);
    for (int z = 0; z < 4; ++z) {
        const float* tz = tmp + (size_t)z * NTOK * DMODEL + base + c0;
        float4 a4 = *(const float4*)tz, b4 = *(const float4*)(tz + 4);
        vals[0] += a4.x; vals[1] += a4.y; vals[2] += a4.z; vals[3] += a4.w;
        vals[4] += b4.x; vals[5] += b4.y; vals[6] += b4.z; vals[7] += b4.w;
    }
    float s = 0.f;
#pragma unroll
    for (int i = 0; i < 8; ++i) s += vals[i];
    for (int off = 1; off < 64; off <<= 1) s += __shfl_xor(s, off, 64);
    float mean = s * (1.0f / DMODEL);
    float vvv = 0.f;
#pragma unroll
    for (int i = 0; i < 8; ++i) { vals[i] -= mean; vvv += vals[i] * vals[i]; }
    for (int off = 1; off < 64; off <<= 1) vvv += __shfl_xor(vvv, off, 64);
    float rstd = rsqrtf(vvv * (1.0f / DMODEL) + 1e-5f);
    float4 g0 = *(const float4*)(g + c0), g1 = *(const float4*)(g + c0 + 4);
    float4 b0 = *(const float4*)(bb + c0), b1 = *(const float4*)(bb + c0 + 4);
    float gs[8] = {g0.x,g0.y,g0.z,g0.w,g1.x,g1.y,g1.z,g1.w};
    float bs[8] = {b0.x,b0.y,b0.z,b0.w,b1.x,b1.y,b1.z,b1.w};
    float o[8]; uint4 pk;
#pragma unroll
    for (int i = 0; i < 8; ++i) o[i] = vals[i] * rstd * gs[i] + bs[i];
    pk.x = pack2(o[0], o[1]); pk.y = pack2(o[2], o[3]);
    pk.z = pack2(o[4], o[5]); pk.w = pack2(o[6], o[7]);
    *(float4*)(xbuf + base + c0)     = make_float4(o[0], o[1], o[2], o[3]);
    *(float4*)(xbuf + base + c0 + 4) = make_float4(o[4], o[5], o[6], o[7]);
    *(uint4*)(xbf + base + c0) = pk;
    if (out) {
        float fr = frac[t];
        *(float4*)(out + base + c0)     = make_float4(o[0]*fr, o[1]*fr, o[2]*fr, o[3]*fr);
        *(float4*)(out + base + c0 + 4) = make_float4(o[4]*fr, o[5]*fr, o[6]*fr, o[7]*fr);
    }
}

extern "C" void kernel_launch(void* const* d_in, const int* in_sizes, int n_in,
                              void* d_out, int out_size, void* d_ws, size_t ws_size,
                              hipStream_t stream) {
    const int*   Z      = (const int*)d_in[0];
    const float* frac   = (const float*)d_in[1];
    const float* emb0   = (const float*)d_in[2];
    const float* p0w    = (const float*)d_in[3];
    const float* p0b    = (const float*)d_in[4];
    const float* emb1   = (const float*)d_in[5];
    const float* p1w    = (const float*)d_in[6];
    const float* p1b    = (const float*)d_in[7];
    const float* emb2   = (const float*)d_in[8];
    const float* p2w    = (const float*)d_in[9];
    const float* p2b    = (const float*)d_in[10];
    const float* keys   = (const float*)d_in[11];
    const float* rw     = (const float*)d_in[12];
    const float* rb     = (const float*)d_in[13];
    const float* ew1    = (const float*)d_in[14];
    const float* eb1    = (const float*)d_in[15];
    const float* ew2    = (const float*)d_in[16];
    const float* eb2    = (const float*)d_in[17];
    const float* qkv_w  = (const float*)d_in[18];
    const float* qkv_b  = (const float*)d_in[19];
    const float* aow    = (const float*)d_in[20];
    const float* aob    = (const float*)d_in[21];
    const float* ln1g   = (const float*)d_in[22];
    const float* ln1b   = (const float*)d_in[23];
    const float* ln2g   = (const float*)d_in[24];
    const float* ln2b   = (const float*)d_in[25];
    const float* fw1    = (const float*)d_in[26];
    const float* fb1    = (const float*)d_in[27];
    const float* fw2    = (const float*)d_in[28];
    const float* fb2    = (const float*)d_in[29];
    float* out = (float*)d_out;

    // workspace layout (same proven budget as R2-R4, ~67 MB)
    char* p = (char*)d_ws;
    char* U = p;
    ushort_t* vbf   = (ushort_t*)U;                               // 864*512*2
    ushort_t* h     = (ushort_t*)(U + 884736);                    // 3456*2048*2
    float*    yall  = (float*)(U + 884736 + 14155776);            // 2*3456*512*4
    ushort_t* qkvwt = (ushort_t*)U;                               // transformer wt (after fuse)
    ushort_t* aowt  = qkvwt + 3 * 1536 * 512;
    ushort_t* fw1t  = aowt  + 3 * 512 * 512;
    ushort_t* fw2t  = fw1t  + 3 * 2048 * 512;
    p = U + 884736 + 14155776 + 14155776;
    float* xbuf = (float*)p;            p += 288 * 512 * 4;
    ushort_t* xbf = (ushort_t*)p;       p += 288 * 512 * 2;
    ushort_t* qkvb = (ushort_t*)p;      p += 288 * 1536 * 2;
    float* tmp  = (float*)p;            p += 4 * 288 * 512 * 4;
    ushort_t* f1b = (ushort_t*)p;       p += 288 * 2048 * 2;
    float* w4   = (float*)p;            p += 3456 * 4;
    int* idx4   = (int*)p;              p += 3456 * 4;
    int* offs   = (int*)p;              p += 256;
    int* rows_tv= (int*)p;              p += 3456 * 4;
    int* rows_s = (int*)p;              p += 3456 * 4;
    int* seg_e  = (int*)p;              p += 128 * 4;
    int* seg_r0 = (int*)p;              p += 128 * 4;
    int* nseg   = (int*)p;              p += 256;
    ushort_t* wt = (ushort_t*)p;        // 16*2048*512*2 = 33.6 MB (ew1t then ew2t)

    // D1: build_tokens + transpose ew1 (independent, fused)
    front_kernel<<<dim3(NTV + 4096), dim3(256), 0, stream>>>(
        Z, emb0, p0w, p0b, emb1, p1w, p1b, emb2, p2w, p2b,
        keys, rw, rb, vbf, w4, idx4, ew1, wt);
    // D2
    route_kernel<<<dim3(1), dim3(256), 0, stream>>>(idx4, offs, rows_tv, rows_s,
                                                    seg_e, seg_r0, nseg);
    // D3
    moe_gemm1<<<dim3(2048 / 64, MAXSEG), dim3(256), 0, stream>>>(
        vbf, rows_tv, offs, seg_e, seg_r0, nseg, wt, eb1, h);
    // D4
    transpose_to_bf16<<<dim3(512 / 64, 2048 / 64, 16), dim3(256), 0, stream>>>(ew2, wt, 2048, 512);
    // D5
    moe_gemm2<<<dim3(512 / 64, MAXSEG, 2), dim3(256), 0, stream>>>(
        h, rows_s, offs, seg_e, seg_r0, nseg, wt, eb2, yall);
    // D6
    fuse_kernel<<<dim3(NTOK), dim3(256), 0, stream>>>(yall, w4, frac, xbuf, xbf);
    // D7 (yall/vbf/h dead now; overwrite U with transformer weights)
    transpose_jobs<<<dim3(2304), dim3(256), 0, stream>>>(
        qkv_w, aow, fw1, fw2, qkvwt, aowt, fw1t, fw2t);

    for (int i = 0; i < 3; ++i) {
        qkv_kernel<<<dim3(108), dim3(256), 0, stream>>>(
            xbf, qkvwt + (size_t)i * 1536 * 512, qkv_b + i * 1536, qkvb);
        attn_block<<<dim3(32), dim3(256), 0, stream>>>(
            qkvb, aowt + (size_t)i * 512 * 512, aob + i * 512,
            xbuf, xbf, ln1g + i * 512, ln1b + i * 512);
        ffn1_kernel<<<dim3(144), dim3(256), 0, stream>>>(
            xbf, fw1t + (size_t)i * 2048 * 512, fb1 + i * 2048, f1b);
        ffn2_kernel<<<dim3(144), dim3(256), 0, stream>>>(
            f1b, fw2t + (size_t)i * 512 * 2048, fb2 + i * 512, tmp);
        ln2_kernel<<<dim3(72), dim3(256), 0, stream>>>(
            xbuf, xbf, tmp, ln2g + i * 512, ln2b + i * 512,
            (i == 2) ? out : nullptr, frac);
    }
}

// Round 6
// 537.921 us; speedup vs baseline: 2.1424x; 1.0238x over previous
//
#include <hip/hip_runtime.h>
#include <hip/hip_bf16.h>
#include <math.h>

#define NTOK   288      // B*L
#define NV     3
#define NTV    864      // NV*NTOK
#define NSEL   3456     // NTV*4
#define DMODEL 512
#define NEXP   16
#define TOPK   4
#define HFF    2048
#define RESN   5000
#define MAXSEG 70

typedef short v8s __attribute__((ext_vector_type(8)));
typedef float v4f __attribute__((ext_vector_type(4)));
typedef unsigned short ushort_t;

__device__ __forceinline__ float gelu_exact(float x) {
    return 0.5f * x * (1.0f + erff(x * 0.70710678118654752f));
}
__device__ __forceinline__ unsigned f2bf1(float f) {
    unsigned u = __builtin_bit_cast(unsigned, f);
    return (u + 0x7fffu + ((u >> 16) & 1u)) >> 16;
}
__device__ __forceinline__ unsigned pack2(float a, float b) {
    return f2bf1(a) | (f2bf1(b) << 16);
}
__device__ __forceinline__ float bf2f(ushort_t u) {
    return __builtin_bit_cast(float, (unsigned)u << 16);
}

// ---------------- transpose tile helper: [K][N] -> [N][K] bf16 ----------------
__device__ __forceinline__ void tile_transpose(
    const float* __restrict__ src_b, ushort_t* __restrict__ out_b,
    int K, int N, int k0, int n0, int tid)
{
    __shared__ ushort_t T[64 * 72];
    int r = tid >> 2, c = tid & 3;
    const float* src = src_b + (size_t)(k0 + r) * N + n0 + c * 16;
    float4 f0 = *(const float4*)(src + 0);
    float4 f1 = *(const float4*)(src + 4);
    float4 f2 = *(const float4*)(src + 8);
    float4 f3 = *(const float4*)(src + 12);
    uint4 u0, u1;
    u0.x = pack2(f0.x, f0.y); u0.y = pack2(f0.z, f0.w);
    u0.z = pack2(f1.x, f1.y); u0.w = pack2(f1.z, f1.w);
    u1.x = pack2(f2.x, f2.y); u1.y = pack2(f2.z, f2.w);
    u1.z = pack2(f3.x, f3.y); u1.w = pack2(f3.z, f3.w);
    *(uint4*)&T[r * 72 + c * 16]     = u0;
    *(uint4*)&T[r * 72 + c * 16 + 8] = u1;
    __syncthreads();
    uint4 o0, o1;
#pragma unroll
    for (int j = 0; j < 16; j += 2) {
        unsigned lo = T[(c * 16 + j)     * 72 + r];
        unsigned hi = T[(c * 16 + j + 1) * 72 + r];
        if (j < 8) ((unsigned*)&o0)[j >> 1] = lo | (hi << 16);
        else       ((unsigned*)&o1)[(j - 8) >> 1] = lo | (hi << 16);
    }
    ushort_t* dst = out_b + (size_t)(n0 + r) * K + k0 + c * 16;
    *(uint4*)(dst)     = o0;
    *(uint4*)(dst + 8) = o1;
}

// ---------------- build_tokens: f-split across 4 waves ----------------
__global__ __launch_bounds__(256) void front_kernel(
    const int* __restrict__ Z,
    const float* __restrict__ emb0, const float* __restrict__ p0w, const float* __restrict__ p0b,
    const float* __restrict__ emb1, const float* __restrict__ p1w, const float* __restrict__ p1b,
    const float* __restrict__ emb2, const float* __restrict__ p2w, const float* __restrict__ p2b,
    const float* __restrict__ keys, const float* __restrict__ router_w, const float* __restrict__ router_b,
    ushort_t* __restrict__ vbf, float* __restrict__ w4, int* __restrict__ idx4)
{
    int tv = blockIdx.x;
    int vi = tv / NTOK, t = tv % NTOK;
    int tid = threadIdx.x;
    int lane = tid & 63, wv = tid >> 6;

    const float* emb; const float* pw; const float* pb; int F;
    if (vi == 0)      { emb = emb0; pw = p0w; pb = p0b; F = 200; }
    else if (vi == 1) { emb = emb1; pw = p1w; pb = p1b; F = 132; }
    else              { emb = emb2; pw = p2w; pb = p2b; F = 112; }
    const float* rw = router_w + (size_t)vi * DMODEL * NEXP;
    const float* rb = router_b + vi * NEXP;

    __shared__ float er[200];
    __shared__ float part[4][DMODEL];
    __shared__ float vs[DMODEL];
    __shared__ float red[256];
    __shared__ float logits[NEXP];
    __shared__ float vsq_s;

    int z = Z[t];
    for (int f = tid; f < F; f += 256) er[f] = emb[(size_t)z * F + f];
    __syncthreads();

    // wave wv sums f = wv, wv+4, ... for its 8 columns per lane
    int c0 = lane * 8;
    float pa[8] = {0.f, 0.f, 0.f, 0.f, 0.f, 0.f, 0.f, 0.f};
    for (int f = wv; f < F; f += 4) {
        float e = er[f];
        const float* prow = pw + (size_t)f * DMODEL + c0;
        float4 w0 = *(const float4*)(prow);
        float4 w1 = *(const float4*)(prow + 4);
        pa[0] += e * w0.x; pa[1] += e * w0.y; pa[2] += e * w0.z; pa[3] += e * w0.w;
        pa[4] += e * w1.x; pa[5] += e * w1.y; pa[6] += e * w1.z; pa[7] += e * w1.w;
    }
    *(float4*)&part[wv][c0]     = make_float4(pa[0], pa[1], pa[2], pa[3]);
    *(float4*)&part[wv][c0 + 4] = make_float4(pa[4], pa[5], pa[6], pa[7]);
    __syncthreads();

    float a0 = pb[tid]       + part[0][tid]       + part[1][tid]       + part[2][tid]       + part[3][tid];
    float a1 = pb[tid + 256] + part[0][tid + 256] + part[1][tid + 256] + part[2][tid + 256] + part[3][tid + 256];
    vs[tid] = a0; vs[tid + 256] = a1;
    vbf[(size_t)tv * DMODEL + tid]       = (ushort_t)f2bf1(a0);
    vbf[(size_t)tv * DMODEL + tid + 256] = (ushort_t)f2bf1(a1);

    red[tid] = a0 * a0 + a1 * a1;
    __syncthreads();
    for (int s = 128; s > 0; s >>= 1) { if (tid < s) red[tid] += red[tid + s]; __syncthreads(); }
    if (tid == 0) vsq_s = red[0];
    __syncthreads();
    float vsq = vsq_s;

    for (int ei = 0; ei < 4; ++ei) {
        int e = wv * 4 + ei;
        float p = 0.0f;
        for (int d = lane; d < DMODEL; d += 64) {
            float vvv = vs[d];
            float kk = keys[e * DMODEL + d];
            p += vvv * rw[d * NEXP + e] - kk * (kk - 2.0f * vvv);
        }
        for (int off = 32; off > 0; off >>= 1) p += __shfl_down(p, off, 64);
        if (lane == 0) logits[e] = -vsq + p + rb[e];
    }
    __syncthreads();

    if (tid == 0) {
        float lv[NEXP];
        for (int e = 0; e < NEXP; ++e) lv[e] = logits[e];
        bool used[NEXP] = {false};
        int   tk[TOPK]; float tval[TOPK];
        for (int k = 0; k < TOPK; ++k) {
            int best = -1; float bv = -1e30f;
            for (int e = 0; e < NEXP; ++e)
                if (!used[e] && lv[e] > bv) { bv = lv[e]; best = e; }
            used[best] = true; tk[k] = best; tval[k] = bv;
        }
        float m = tval[0], sum = 0.0f, ww[TOPK];
        for (int k = 0; k < TOPK; ++k) { ww[k] = expf(tval[k] - m); sum += ww[k]; }
        for (int k = 0; k < TOPK; ++k) {
            w4[tv * TOPK + k] = ww[k] / sum;
            idx4[tv * TOPK + k] = tk[k];
        }
    }
}

// ---------------- route: compact rows per expert + 64-row segment list ----------------
__global__ __launch_bounds__(256) void route_kernel(
    const int* __restrict__ idx4, int* __restrict__ offs,
    int* __restrict__ rows_tv, int* __restrict__ rows_s,
    int* __restrict__ seg_e, int* __restrict__ seg_r0, int* __restrict__ nseg)
{
    __shared__ int cnt[NEXP], cur[NEXP], offsh[NEXP + 1];
    int tid = threadIdx.x;
    if (tid < NEXP) cnt[tid] = 0;
    __syncthreads();
    for (int s = tid; s < NSEL; s += 256) atomicAdd(&cnt[idx4[s]], 1);
    __syncthreads();
    if (tid == 0) {
        int o = 0;
        for (int e = 0; e < NEXP; ++e) { offsh[e] = o; o += cnt[e]; }
        offsh[NEXP] = o;
        int ns = 0;
        for (int e = 0; e < NEXP; ++e)
            for (int s = offsh[e]; s < offsh[e + 1]; s += 64) {
                seg_e[ns] = e; seg_r0[ns] = s; ++ns;
            }
        nseg[0] = ns;
    }
    __syncthreads();
    if (tid < NEXP) cur[tid] = offsh[tid];
    if (tid <= NEXP) offs[tid] = offsh[tid];
    __syncthreads();
    for (int s = tid; s < NSEL; s += 256) {
        int e = idx4[s];
        int pos = atomicAdd(&cur[e], 1);
        rows_tv[pos] = s >> 2;
        rows_s[pos]  = s;
    }
}

// ---------------- MoE phase 1: in-kernel fp32->bf16 B transpose, segment-parallel ----------------
// grid (2048/64, MAXSEG)
__global__ __launch_bounds__(256) void moe_gemm1(
    const ushort_t* __restrict__ vbf, const int* __restrict__ rows_tv,
    const int* __restrict__ offs,
    const int* __restrict__ seg_e, const int* __restrict__ seg_r0, const int* __restrict__ nseg,
    const float* __restrict__ ew1, const float* __restrict__ eb1, ushort_t* __restrict__ h)
{
    if ((int)blockIdx.y >= nseg[0]) return;
    int e = seg_e[blockIdx.y], r0 = seg_r0[blockIdx.y];
    int rend = offs[e + 1];
    int n0 = blockIdx.x * 64;
    const float* W = ew1 + (size_t)e * DMODEL * HFF;   // [512][2048] fp32
    const float* bias = eb1 + (size_t)e * HFF;
    __shared__ ushort_t Bs[64 * 72];
    unsigned* bs32 = (unsigned*)Bs;
    int tid = threadIdx.x, wv = tid >> 6, lane = tid & 63, lm = lane & 15, lq = lane >> 4;
    int kk2 = tid >> 3;            // 0..31 -> k rows 2*kk2, 2*kk2+1
    int nn0 = (tid & 7) * 8;       // 8 n columns

    int rA = min(r0 + wv * 16 + lm, rend - 1);
    const ushort_t* arow = vbf + (size_t)rows_tv[rA] * DMODEL;

    v4f acc[4];
#pragma unroll
    for (int nt = 0; nt < 4; ++nt) acc[nt] = (v4f){0.f, 0.f, 0.f, 0.f};

    for (int kp = 0; kp < DMODEL; kp += 64) {
        const float* src0 = W + (size_t)(kp + 2 * kk2) * HFF + n0 + nn0;
        float4 r0a = *(const float4*)(src0);
        float4 r0b = *(const float4*)(src0 + 4);
        float4 r1a = *(const float4*)(src0 + HFF);
        float4 r1b = *(const float4*)(src0 + HFF + 4);
        bs32[(nn0 + 0) * 36 + kk2] = pack2(r0a.x, r1a.x);
        bs32[(nn0 + 1) * 36 + kk2] = pack2(r0a.y, r1a.y);
        bs32[(nn0 + 2) * 36 + kk2] = pack2(r0a.z, r1a.z);
        bs32[(nn0 + 3) * 36 + kk2] = pack2(r0a.w, r1a.w);
        bs32[(nn0 + 4) * 36 + kk2] = pack2(r0b.x, r1b.x);
        bs32[(nn0 + 5) * 36 + kk2] = pack2(r0b.y, r1b.y);
        bs32[(nn0 + 6) * 36 + kk2] = pack2(r0b.z, r1b.z);
        bs32[(nn0 + 7) * 36 + kk2] = pack2(r0b.w, r1b.w);
        __syncthreads();
#pragma unroll
        for (int s = 0; s < 64; s += 32) {
            v8s a = *(const v8s*)(arow + kp + s + lq * 8);
#pragma unroll
            for (int nt = 0; nt < 4; ++nt) {
                v8s b = *(const v8s*)&Bs[(nt * 16 + lm) * 72 + s + lq * 8];
                acc[nt] = __builtin_amdgcn_mfma_f32_16x16x32_bf16(a, b, acc[nt], 0, 0, 0);
            }
        }
        __syncthreads();
    }
#pragma unroll
    for (int nt = 0; nt < 4; ++nt) {
        int col = n0 + nt * 16 + lm;
        float bv = bias[col];
#pragma unroll
        for (int i = 0; i < 4; ++i) {
            int row = r0 + wv * 16 + lq * 4 + i;
            if (row < rend) {
                float val = gelu_exact(acc[nt][i] + bv);
                h[(size_t)row * HFF + col] = (ushort_t)f2bf1(val);
            }
        }
    }
}

// ---------------- MoE phase 2: in-kernel B transpose, K-split z=2 ----------------
// grid (512/64, MAXSEG, 2)
__global__ __launch_bounds__(256) void moe_gemm2(
    const ushort_t* __restrict__ h, const int* __restrict__ rows_s,
    const int* __restrict__ offs,
    const int* __restrict__ seg_e, const int* __restrict__ seg_r0, const int* __restrict__ nseg,
    const float* __restrict__ ew2, const float* __restrict__ eb2, float* __restrict__ yall)
{
    if ((int)blockIdx.y >= nseg[0]) return;
    int e = seg_e[blockIdx.y], r0 = seg_r0[blockIdx.y];
    int rend = offs[e + 1];
    int n0 = blockIdx.x * 64;
    int z = blockIdx.z;
    int kp0 = z * (HFF / 2);
    const float* W = ew2 + (size_t)e * HFF * DMODEL;   // [2048][512] fp32
    const float* bias = eb2 + (size_t)e * DMODEL;
    float* yz = yall + (size_t)z * NSEL * DMODEL;
    __shared__ ushort_t Bs[64 * 72];
    unsigned* bs32 = (unsigned*)Bs;
    int tid = threadIdx.x, wv = tid >> 6, lane = tid & 63, lm = lane & 15, lq = lane >> 4;
    int kk2 = tid >> 3;
    int nn0 = (tid & 7) * 8;

    int rA = min(r0 + wv * 16 + lm, rend - 1);
    const ushort_t* arow = h + (size_t)rA * HFF;

    v4f acc[4];
#pragma unroll
    for (int nt = 0; nt < 4; ++nt) acc[nt] = (v4f){0.f, 0.f, 0.f, 0.f};

    for (int kp = kp0; kp < kp0 + HFF / 2; kp += 64) {
        const float* src0 = W + (size_t)(kp + 2 * kk2) * DMODEL + n0 + nn0;
        float4 r0a = *(const float4*)(src0);
        float4 r0b = *(const float4*)(src0 + 4);
        float4 r1a = *(const float4*)(src0 + DMODEL);
        float4 r1b = *(const float4*)(src0 + DMODEL + 4);
        bs32[(nn0 + 0) * 36 + kk2] = pack2(r0a.x, r1a.x);
        bs32[(nn0 + 1) * 36 + kk2] = pack2(r0a.y, r1a.y);
        bs32[(nn0 + 2) * 36 + kk2] = pack2(r0a.z, r1a.z);
        bs32[(nn0 + 3) * 36 + kk2] = pack2(r0a.w, r1a.w);
        bs32[(nn0 + 4) * 36 + kk2] = pack2(r0b.x, r1b.x);
        bs32[(nn0 + 5) * 36 + kk2] = pack2(r0b.y, r1b.y);
        bs32[(nn0 + 6) * 36 + kk2] = pack2(r0b.z, r1b.z);
        bs32[(nn0 + 7) * 36 + kk2] = pack2(r0b.w, r1b.w);
        __syncthreads();
#pragma unroll
        for (int s = 0; s < 64; s += 32) {
            v8s a = *(const v8s*)(arow + kp + s + lq * 8);
#pragma unroll
            for (int nt = 0; nt < 4; ++nt) {
                v8s b = *(const v8s*)&Bs[(nt * 16 + lm) * 72 + s + lq * 8];
                acc[nt] = __builtin_amdgcn_mfma_f32_16x16x32_bf16(a, b, acc[nt], 0, 0, 0);
            }
        }
        __syncthreads();
    }
#pragma unroll
    for (int nt = 0; nt < 4; ++nt) {
        int col = n0 + nt * 16 + lm;
        float bv = (z == 0) ? bias[col] : 0.0f;
#pragma unroll
        for (int i = 0; i < 4; ++i) {
            int row = r0 + wv * 16 + lq * 4 + i;
            if (row < rend) {
                yz[(size_t)rows_s[row] * DMODEL + col] = acc[nt][i] + bv;
            }
        }
    }
}

// ---------------- fuse: MoE gather + PE  (+ transformer weight transposes A) ----------------
__global__ __launch_bounds__(256) void fuse_kernel(
    const float* __restrict__ y_all, const float* __restrict__ w4,
    const float* __restrict__ frac, float* __restrict__ x, ushort_t* __restrict__ xbf,
    const float* __restrict__ qkvw, const float* __restrict__ aow, const float* __restrict__ fw1,
    ushort_t* __restrict__ qkvwt, ushort_t* __restrict__ aowt, ushort_t* __restrict__ fw1t)
{
    int tid = threadIdx.x;
    if (blockIdx.x >= NTOK) {
        int b = blockIdx.x - NTOK;          // 0..1535
        const float* src; ushort_t* dst; int K, N, nt;
        if (b < 576)      {          src = qkvw; dst = qkvwt; K = 512; N = 1536; nt = 24; }
        else if (b < 768) { b -= 576; src = aow;  dst = aowt;  K = 512; N = 512;  nt = 8;  }
        else              { b -= 768; src = fw1;  dst = fw1t;  K = 512; N = 2048; nt = 32; }
        int per = nt * (K / 64);
        int z = b / per, r = b % per;
        size_t boff = (size_t)z * (size_t)K * N;
        tile_transpose(src + boff, dst + boff, K, N, (r / nt) * 64, (r % nt) * 64, tid);
        return;
    }
    int t = blockIdx.x;
    __shared__ float wsh[12];
    __shared__ int idxsh[2];
    if (tid < 12) {
        int vi = tid >> 2, kk = tid & 3;
        wsh[tid] = w4[((size_t)vi * NTOK + t) * TOPK + kk];
    }
    if (tid == 0) {
        double r = (double)frac[t];
        double rl = fmax(r, 1.0 / RESN);
        int il = (int)rint(rl * RESN) - 1;
        idxsh[0] = min(max(il, 0), RESN - 1);
        double lg = log2(r);
        double rg = 0.0025 * lg * lg;
        rg = fmin(rg, 1.0);
        rg = fmax(rg, 1.0 / RESN);
        int ig = (int)rint(rg * RESN) - 1;
        idxsh[1] = min(max(ig, 0), RESN - 1);
    }
    __syncthreads();
    for (int d = tid; d < DMODEL; d += 256) {
        float acc = 0.0f;
        for (int c = 0; c < 12; ++c) {
            int vi = c >> 2, kk = c & 3;
            size_t s = ((size_t)vi * NTOK + t) * TOPK + kk;
            float y = y_all[s * DMODEL + d] + y_all[(size_t)NSEL * DMODEL + s * DMODEL + d];
            acc += wsh[c] * y;
        }
        int cc  = (d < 256) ? d : d - 256;
        int idx = (d < 256) ? idxsh[0] : idxsh[1];
        double arg = (double)idx / pow(50.0, 2.0 * (double)cc / 256.0);
        double pe = (cc & 1) ? cos(arg) : sin(arg);
        float val = acc + (float)pe;
        x[(size_t)t * DMODEL + d] = val;
        xbf[(size_t)t * DMODEL + d] = (ushort_t)f2bf1(val);
    }
}

// ---------------- per-wave 16x64 GEMM unit (bf16 A [*][K], Wt [N][K]) ----------------
__device__ __forceinline__ void gemm_wave_unit(
    const ushort_t* __restrict__ A, int K, const ushort_t* __restrict__ Wt,
    int m0, int n0, int kp0, int Klen, int lm, int lq, v4f acc[4])
{
    const ushort_t* arow  = A  + (size_t)(m0 + lm) * K + kp0;
    const ushort_t* wrow0 = Wt + (size_t)(n0 + lm) * K + kp0;
    for (int ks = 0; ks < Klen; ks += 32) {
        v8s a = *(const v8s*)(arow + ks + lq * 8);
#pragma unroll
        for (int nt = 0; nt < 4; ++nt) {
            v8s b = *(const v8s*)(wrow0 + (size_t)nt * 16 * K + ks + lq * 8);
            acc[nt] = __builtin_amdgcn_mfma_f32_16x16x32_bf16(a, b, acc[nt], 0, 0, 0);
        }
    }
}

// ---------------- qkv GEMM (108 blocks) + fw2 transpose tail (768 blocks, L0 only) ----------------
__global__ __launch_bounds__(256) void qkv_kernel(
    const ushort_t* __restrict__ xbf, const ushort_t* __restrict__ Wq,
    const float* __restrict__ bq, ushort_t* __restrict__ qkvb,
    const float* __restrict__ fw2, ushort_t* __restrict__ fw2t)
{
    int tid = threadIdx.x;
    if (blockIdx.x >= 108) {
        int b = blockIdx.x - 108;          // 0..767 : fw2 [2048][512], nt=8, kt=32
        int z = b / 256, r = b % 256;
        int n0 = (r % 8) * 64, k0 = (r / 8) * 64;
        size_t boff = (size_t)z * 2048 * 512;
        tile_transpose(fw2 + boff, fw2t + boff, 2048, 512, k0, n0, tid);
        return;
    }
    int wv = tid >> 6, lane = tid & 63, lm = lane & 15, lq = lane >> 4;
    int gw = blockIdx.x * 4 + wv;
    int m0 = (gw / 24) * 16, n0 = (gw % 24) * 64;
    v4f acc[4];
#pragma unroll
    for (int nt = 0; nt < 4; ++nt) acc[nt] = (v4f){0.f, 0.f, 0.f, 0.f};
    gemm_wave_unit(xbf, 512, Wq, m0, n0, 0, 512, lm, lq, acc);
#pragma unroll
    for (int nt = 0; nt < 4; ++nt) {
        int col = n0 + nt * 16 + lm;
        float bv = bq[col];
#pragma unroll
        for (int i = 0; i < 4; ++i) {
            int row = m0 + lq * 4 + i;
            qkvb[(size_t)row * 1536 + col] = (ushort_t)f2bf1(acc[nt][i] + bv);
        }
    }
}

// ---------------- attention + oproj + residual + ln1: one block per batch ----------------
__global__ __launch_bounds__(256) void attn_block(
    const ushort_t* __restrict__ qkvb, const ushort_t* __restrict__ Wot,
    const float* __restrict__ bo, float* __restrict__ xbuf, ushort_t* __restrict__ xbf,
    const float* __restrict__ g, const float* __restrict__ bb)
{
    int bbk = blockIdx.x, t0 = bbk * 9;
    int tid = threadIdx.x, wv = tid >> 6, lane = tid & 63, lm = lane & 15, lq = lane >> 4;

    __shared__ ushort_t qkvs[9][1536];
    __shared__ ushort_t osh[16][520];
    __shared__ float sc[8][9][9];
    __shared__ float res[9][512];

    for (int idx = tid; idx < 9 * 192; idx += 256) {
        int r = idx / 192, c = (idx % 192) * 8;
        *(uint4*)&qkvs[r][c] = *(const uint4*)(qkvb + (size_t)(t0 + r) * 1536 + c);
    }
    for (int idx = tid; idx < 16 * 65; idx += 256) {
        *(uint4*)&osh[idx / 65][(idx % 65) * 8] = (uint4){0, 0, 0, 0};
    }
    __syncthreads();

    for (int idx = tid; idx < 648; idx += 256) {
        int hh = idx / 81, ij = idx % 81, i = ij / 9, j = ij % 9;
        const ushort_t* qr = &qkvs[i][hh * 64];
        const ushort_t* kr = &qkvs[j][512 + hh * 64];
        float s = 0.0f;
        for (int d = 0; d < 64; ++d) s += bf2f(qr[d]) * bf2f(kr[d]);
        sc[hh][i][j] = s * 0.125f;
    }
    __syncthreads();
    if (tid < 72) {
        int hh = tid / 9, i = tid % 9;
        float m = -1e30f;
        for (int j = 0; j < 9; ++j) m = fmaxf(m, sc[hh][i][j]);
        float sum = 0.0f, e[9];
        for (int j = 0; j < 9; ++j) { e[j] = expf(sc[hh][i][j] - m); sum += e[j]; }
        for (int j = 0; j < 9; ++j) sc[hh][i][j] = e[j] / sum;
    }
    __syncthreads();
    for (int idx = tid; idx < 4608; idx += 256) {
        int hh = idx / 576, r = idx % 576, i = r / 64, d = r % 64;
        float acc = 0.0f;
        for (int j = 0; j < 9; ++j) acc += sc[hh][i][j] * bf2f(qkvs[j][1024 + hh * 64 + d]);
        osh[i][hh * 64 + d] = (ushort_t)f2bf1(acc);
    }
    __syncthreads();

    v4f acc[8];
#pragma unroll
    for (int nt = 0; nt < 8; ++nt) acc[nt] = (v4f){0.f, 0.f, 0.f, 0.f};
    int n0w = wv * 128;
    for (int ks = 0; ks < 512; ks += 32) {
        v8s a = *(const v8s*)&osh[lm][ks + lq * 8];
#pragma unroll
        for (int nt = 0; nt < 8; ++nt) {
            v8s b = *(const v8s*)(Wot + (size_t)(n0w + nt * 16 + lm) * 512 + ks + lq * 8);
            acc[nt] = __builtin_amdgcn_mfma_f32_16x16x32_bf16(a, b, acc[nt], 0, 0, 0);
        }
    }
#pragma unroll
    for (int nt = 0; nt < 8; ++nt) {
        int col = n0w + nt * 16 + lm;
        float bv = bo[col];
#pragma unroll
        for (int i = 0; i < 4; ++i) {
            int row = lq * 4 + i;
            if (row < 9) res[row][col] = acc[nt][i] + bv;
        }
    }
    __syncthreads();

    for (int r = wv; r < 9; r += 4) {
        int t = t0 + r;
        size_t base = (size_t)t * DMODEL;
        int c0 = lane * 8;
        float vals[8];
        float4 x0 = *(const float4*)(xbuf + base + c0);
        float4 x1 = *(const float4*)(xbuf + base + c0 + 4);
        vals[0] = x0.x + res[r][c0 + 0]; vals[1] = x0.y + res[r][c0 + 1];
        vals[2] = x0.z + res[r][c0 + 2]; vals[3] = x0.w + res[r][c0 + 3];
        vals[4] = x1.x + res[r][c0 + 4]; vals[5] = x1.y + res[r][c0 + 5];
        vals[6] = x1.z + res[r][c0 + 6]; vals[7] = x1.w + res[r][c0 + 7];
        float s = 0.f;
#pragma unroll
        for (int i = 0; i < 8; ++i) s += vals[i];
        for (int off = 1; off < 64; off <<= 1) s += __shfl_xor(s, off, 64);
        float mean = s * (1.0f / DMODEL);
        float vvv = 0.f;
#pragma unroll
        for (int i = 0; i < 8; ++i) { vals[i] -= mean; vvv += vals[i] * vals[i]; }
        for (int off = 1; off < 64; off <<= 1) vvv += __shfl_xor(vvv, off, 64);
        float rstd = rsqrtf(vvv * (1.0f / DMODEL) + 1e-5f);
        float4 g0 = *(const float4*)(g + c0), g1 = *(const float4*)(g + c0 + 4);
        float4 b0 = *(const float4*)(bb + c0), b1 = *(const float4*)(bb + c0 + 4);
        float gs[8] = {g0.x,g0.y,g0.z,g0.w,g1.x,g1.y,g1.z,g1.w};
        float bs[8] = {b0.x,b0.y,b0.z,b0.w,b1.x,b1.y,b1.z,b1.w};
        float o[8]; uint4 pk;
#pragma unroll
        for (int i = 0; i < 8; ++i) o[i] = vals[i] * rstd * gs[i] + bs[i];
        pk.x = pack2(o[0], o[1]); pk.y = pack2(o[2], o[3]);
        pk.z = pack2(o[4], o[5]); pk.w = pack2(o[6], o[7]);
        *(float4*)(xbuf + base + c0)     = make_float4(o[0], o[1], o[2], o[3]);
        *(float4*)(xbuf + base + c0 + 4) = make_float4(o[4], o[5], o[6], o[7]);
        *(uint4*)(xbf + base + c0) = pk;
    }
}

// ---------------- ffn1: relu(x @ W1^T + b1), 144 blocks ----------------
__global__ __launch_bounds__(256) void ffn1_kernel(
    const ushort_t* __restrict__ xbf, const ushort_t* __restrict__ W1,
    const float* __restrict__ b1, ushort_t* __restrict__ f1b)
{
    int tid = threadIdx.x, wv = tid >> 6, lane = tid & 63, lm = lane & 15, lq = lane >> 4;
    int gw = blockIdx.x * 4 + wv;
    int m0 = (gw / 32) * 16, n0 = (gw % 32) * 64;
    v4f acc[4];
#pragma unroll
    for (int nt = 0; nt < 4; ++nt) acc[nt] = (v4f){0.f, 0.f, 0.f, 0.f};
    gemm_wave_unit(xbf, 512, W1, m0, n0, 0, 512, lm, lq, acc);
#pragma unroll
    for (int nt = 0; nt < 4; ++nt) {
        int col = n0 + nt * 16 + lm;
        float bv = b1[col];
#pragma unroll
        for (int i = 0; i < 4; ++i) {
            int row = m0 + lq * 4 + i;
            f1b[(size_t)row * 2048 + col] = (ushort_t)f2bf1(fmaxf(acc[nt][i] + bv, 0.f));
        }
    }
}

// ---------------- ffn2: K-split z=4 partials, 144 blocks ----------------
__global__ __launch_bounds__(256) void ffn2_kernel(
    const ushort_t* __restrict__ f1b, const ushort_t* __restrict__ W2,
    const float* __restrict__ b2, float* __restrict__ tmp)
{
    int tid = threadIdx.x, wv = tid >> 6, lane = tid & 63, lm = lane & 15, lq = lane >> 4;
    int gw = blockIdx.x * 4 + wv;
    int z = gw / 144, rest = gw % 144;
    int m0 = (rest / 8) * 16, n0 = (rest % 8) * 64;
    v4f acc[4];
#pragma unroll
    for (int nt = 0; nt < 4; ++nt) acc[nt] = (v4f){0.f, 0.f, 0.f, 0.f};
    gemm_wave_unit(f1b, 2048, W2, m0, n0, z * 512, 512, lm, lq, acc);
    float* tz = tmp + (size_t)z * NTOK * DMODEL;
#pragma unroll
    for (int nt = 0; nt < 4; ++nt) {
        int col = n0 + nt * 16 + lm;
        float bv = (z == 0) ? b2[col] : 0.0f;
#pragma unroll
        for (int i = 0; i < 4; ++i) {
            int row = m0 + lq * 4 + i;
            tz[(size_t)row * 512 + col] = acc[nt][i] + bv;
        }
    }
}

// ---------------- ln2: residual(4 partials) + LN (+final scale) ----------------
__global__ __launch_bounds__(256) void ln2_kernel(
    float* __restrict__ xbuf, ushort_t* __restrict__ xbf,
    const float* __restrict__ tmp,
    const float* __restrict__ g, const float* __restrict__ bb,
    float* __restrict__ out, const float* __restrict__ frac)
{
    int tid = threadIdx.x, wv = tid >> 6, lane = tid & 63;
    int t = blockIdx.x * 4 + wv;
    size_t base = (size_t)t * DMODEL;
    int c0 = lane * 8;
    float vals[8];
    *(float4*)(vals)     = *(const float4*)(xbuf + base + c0);
    *(float4*)(vals + 4) = *(const float4*)(xbuf + base + c0 + 4);
    for (int z = 0; z < 4; ++z) {
        const float* tz = tmp + (size_t)z * NTOK * DMODEL + base + c0;
        float4 a4 = *(const float4*)tz, b4 = *(const float4*)(tz + 4);
        vals[0] += a4.x; vals[1] += a4.y; vals[2] += a4.z; vals[3] += a4.w;
        vals[4] += b4.x; vals[5] += b4.y; vals[6] += b4.z; vals[7] += b4.w;
    }
    float s = 0.f;
#pragma unroll
    for (int i = 0; i < 8; ++i) s += vals[i];
    for (int off = 1; off < 64; off <<= 1) s += __shfl_xor(s, off, 64);
    float mean = s * (1.0f / DMODEL);
    float vvv = 0.f;
#pragma unroll
    for (int i = 0; i < 8; ++i) { vals[i] -= mean; vvv += vals[i] * vals[i]; }
    for (int off = 1; off < 64; off <<= 1) vvv += __shfl_xor(vvv, off, 64);
    float rstd = rsqrtf(vvv * (1.0f / DMODEL) + 1e-5f);
    float4 g0 = *(const float4*)(g + c0), g1 = *(const float4*)(g + c0 + 4);
    float4 b0 = *(const float4*)(bb + c0), b1 = *(const float4*)(bb + c0 + 4);
    float gs[8] = {g0.x,g0.y,g0.z,g0.w,g1.x,g1.y,g1.z,g1.w};
    float bs[8] = {b0.x,b0.y,b0.z,b0.w,b1.x,b1.y,b1.z,b1.w};
    float o[8]; uint4 pk;
#pragma unroll
    for (int i = 0; i < 8; ++i) o[i] = vals[i] * rstd * gs[i] + bs[i];
    pk.x = pack2(o[0], o[1]); pk.y = pack2(o[2], o[3]);
    pk.z = pack2(o[4], o[5]); pk.w = pack2(o[6], o[7]);
    *(float4*)(xbuf + base + c0)     = make_float4(o[0], o[1], o[2], o[3]);
    *(float4*)(xbuf + base + c0 + 4) = make_float4(o[4], o[5], o[6], o[7]);
    *(uint4*)(xbf + base + c0) = pk;
    if (out) {
        float fr = frac[t];
        *(float4*)(out + base + c0)     = make_float4(o[0]*fr, o[1]*fr, o[2]*fr, o[3]*fr);
        *(float4*)(out + base + c0 + 4) = make_float4(o[4]*fr, o[5]*fr, o[6]*fr, o[7]*fr);
    }
}

extern "C" void kernel_launch(void* const* d_in, const int* in_sizes, int n_in,
                              void* d_out, int out_size, void* d_ws, size_t ws_size,
                              hipStream_t stream) {
    const int*   Z      = (const int*)d_in[0];
    const float* frac   = (const float*)d_in[1];
    const float* emb0   = (const float*)d_in[2];
    const float* p0w    = (const float*)d_in[3];
    const float* p0b    = (const float*)d_in[4];
    const float* emb1   = (const float*)d_in[5];
    const float* p1w    = (const float*)d_in[6];
    const float* p1b    = (const float*)d_in[7];
    const float* emb2   = (const float*)d_in[8];
    const float* p2w    = (const float*)d_in[9];
    const float* p2b    = (const float*)d_in[10];
    const float* keys   = (const float*)d_in[11];
    const float* rw     = (const float*)d_in[12];
    const float* rb     = (const float*)d_in[13];
    const float* ew1    = (const float*)d_in[14];
    const float* eb1    = (const float*)d_in[15];
    const float* ew2    = (const float*)d_in[16];
    const float* eb2    = (const float*)d_in[17];
    const float* qkv_w  = (const float*)d_in[18];
    const float* qkv_b  = (const float*)d_in[19];
    const float* aow    = (const float*)d_in[20];
    const float* aob    = (const float*)d_in[21];
    const float* ln1g   = (const float*)d_in[22];
    const float* ln1b   = (const float*)d_in[23];
    const float* ln2g   = (const float*)d_in[24];
    const float* ln2b   = (const float*)d_in[25];
    const float* fw1    = (const float*)d_in[26];
    const float* fb1    = (const float*)d_in[27];
    const float* fw2    = (const float*)d_in[28];
    const float* fb2    = (const float*)d_in[29];
    float* out = (float*)d_out;

    // workspace layout (~54 MB, no aliasing)
    char* p = (char*)d_ws;
    ushort_t* vbf  = (ushort_t*)p;      p += 864 * 512 * 2;          // 0.88 MB
    ushort_t* h    = (ushort_t*)p;      p += 3456 * 2048 * 2;        // 14.2 MB
    float* yall    = (float*)p;         p += 2 * 3456 * 512 * 4;     // 14.2 MB
    ushort_t* qkvwt= (ushort_t*)p;      p += 3 * 1536 * 512 * 2;     // 4.7 MB
    ushort_t* aowt = (ushort_t*)p;      p += 3 * 512 * 512 * 2;      // 1.6 MB
    ushort_t* fw1t = (ushort_t*)p;      p += 3 * 2048 * 512 * 2;     // 6.3 MB
    ushort_t* fw2t = (ushort_t*)p;      p += 3 * 512 * 2048 * 2;     // 6.3 MB
    float* xbuf = (float*)p;            p += 288 * 512 * 4;
    ushort_t* xbf = (ushort_t*)p;       p += 288 * 512 * 2;
    ushort_t* qkvb = (ushort_t*)p;      p += 288 * 1536 * 2;
    float* tmp  = (float*)p;            p += 4 * 288 * 512 * 4;
    ushort_t* f1b = (ushort_t*)p;       p += 288 * 2048 * 2;
    float* w4   = (float*)p;            p += 3456 * 4;
    int* idx4   = (int*)p;              p += 3456 * 4;
    int* offs   = (int*)p;              p += 256;
    int* rows_tv= (int*)p;              p += 3456 * 4;
    int* rows_s = (int*)p;              p += 3456 * 4;
    int* seg_e  = (int*)p;              p += 128 * 4;
    int* seg_r0 = (int*)p;              p += 128 * 4;
    int* nseg   = (int*)p;              p += 256;

    front_kernel<<<dim3(NTV), dim3(256), 0, stream>>>(
        Z, emb0, p0w, p0b, emb1, p1w, p1b, emb2, p2w, p2b,
        keys, rw, rb, vbf, w4, idx4);
    route_kernel<<<dim3(1), dim3(256), 0, stream>>>(idx4, offs, rows_tv, rows_s,
                                                    seg_e, seg_r0, nseg);
    moe_gemm1<<<dim3(HFF / 64, MAXSEG), dim3(256), 0, stream>>>(
        vbf, rows_tv, offs, seg_e, seg_r0, nseg, ew1, eb1, h);
    moe_gemm2<<<dim3(DMODEL / 64, MAXSEG, 2), dim3(256), 0, stream>>>(
        h, rows_s, offs, seg_e, seg_r0, nseg, ew2, eb2, yall);
    fuse_kernel<<<dim3(NTOK + 1536), dim3(256), 0, stream>>>(
        yall, w4, frac, xbuf, xbf, qkv_w, aow, fw1, qkvwt, aowt, fw1t);

    for (int i = 0; i < 3; ++i) {
        qkv_kernel<<<dim3(i == 0 ? 108 + 768 : 108), dim3(256), 0, stream>>>(
            xbf, qkvwt + (size_t)i * 1536 * 512, qkv_b + i * 1536, qkvb, fw2, fw2t);
        attn_block<<<dim3(32), dim3(256), 0, stream>>>(
            qkvb, aowt + (size_t)i * 512 * 512, aob + i * 512,
            xbuf, xbf, ln1g + i * 512, ln1b + i * 512);
        ffn1_kernel<<<dim3(144), dim3(256), 0, stream>>>(
            xbf, fw1t + (size_t)i * 2048 * 512, fb1 + i * 2048, f1b);
        ffn2_kernel<<<dim3(144), dim3(256), 0, stream>>>(
            f1b, fw2t + (size_t)i * 512 * 2048, fb2 + i * 512, tmp);
        ln2_kernel<<<dim3(72), dim3(256), 0, stream>>>(
            xbuf, xbf, tmp, ln2g + i * 512, ln2b + i * 512,
            (i == 2) ? out : nullptr, frac);
    }
}